// Round 1
// baseline (153316.162 us; speedup 1.0000x reference)
//
#include <hip/hip_runtime.h>

typedef unsigned int u32;
typedef unsigned short u16;

static constexpr int NWG    = 256;   // 32 batch-groups x 8 h-slices
static constexpr int NTHR   = 256;
static constexpr int NSTEPS = 511;

// ---- workspace layout (bytes) ----
static constexpr size_t K_OFF     = 0;                        // float kg[6][256][128]
static constexpr size_t FLAGS_OFF = 6ull * 256 * 128 * 4;     // u32 flags[256]
static constexpr size_t W0_OFF    = FLAGS_OFF + 4096;         // u16 w0b[256*128]
static constexpr size_t W1_OFF    = W0_OFF + 256 * 128 * 2;   // u16 w1b[256*256]
static constexpr size_t W2_OFF    = W1_OFF + 256 * 256 * 2;   // u16 w2b[4096*256]
static constexpr size_t WS_NEED   = W2_OFF + 4096ull * 256 * 2;

// ---- Tsit5 tableau ----
__device__ static const float AT[6][5] = {
  {0.f, 0.f, 0.f, 0.f, 0.f},
  {0.161f, 0.f, 0.f, 0.f, 0.f},
  {-0.008480655492356989f, 0.335480655492357f, 0.f, 0.f, 0.f},
  {2.8971530571054935f, -6.359448489975075f, 4.3622954328695815f, 0.f, 0.f},
  {5.325864828439257f, -11.748883564062828f, 7.4955393428898365f, -0.09249506636175525f, 0.f},
  {5.86145544294642f, -12.92096931784711f, 8.159367898576159f, -0.071584973281401f, -0.028269050394068383f}
};
__device__ static const float BTab[6] = {
  0.09646076681806523f, 0.01f, 0.4798896504144996f, 1.379008574103742f,
  -3.290069515436081f, 2.324710524099774f
};
__device__ static const float CTab[6] = {0.f, 0.161f, 0.327f, 0.9f, 0.9800255409045097f, 1.f};

__device__ __forceinline__ float blo(u32 u) { return __uint_as_float(u << 16); }
__device__ __forceinline__ float bhi(u32 u) { return __uint_as_float(u & 0xffff0000u); }

// fp32 -> bf16 (RNE), weights only
__global__ void cvt_weights(const float* __restrict__ w0, const float* __restrict__ w1,
                            const float* __restrict__ w2, u16* __restrict__ o0,
                            u16* __restrict__ o1, u16* __restrict__ o2) {
  int i = blockIdx.x * blockDim.x + threadIdx.x;
  auto cv = [](float f) -> u16 {
    u32 u = __float_as_uint(f);
    return (u16)((u + 0x7fffu + ((u >> 16) & 1u)) >> 16);
  };
  if (i < 256 * 128)  o0[i] = cv(w0[i]);
  if (i < 256 * 256)  o1[i] = cv(w1[i]);
  if (i < 4096 * 256) o2[i] = cv(w2[i]);
}

// Persistent kernel: WG = (batch-group bt of 8 rows) x (h-slice hs of 512 GEMM3 cols).
// Front MLP replicated per WG for its 8 rows; GEMM3 slice private; one flag exchange
// of k per stage among the 8 WGs of a group.
__launch_bounds__(NTHR, 1)
__global__ void cde_kernel(const float* __restrict__ ts,
                           const float* __restrict__ cdg, const float* __restrict__ ccg,
                           const float* __restrict__ cbg,
                           const float* __restrict__ x0g, const float* __restrict__ l1w,
                           const float* __restrict__ l1b,
                           const float* __restrict__ b0g, const float* __restrict__ b1g,
                           const float* __restrict__ b2g,
                           const float* __restrict__ l2w, const float* __restrict__ l2b,
                           const u16* __restrict__ w0b, const u16* __restrict__ w1b,
                           const u16* __restrict__ w2b,
                           float* kg, u32* flags, float* __restrict__ outp) {
  // transposed activation tiles: [k][row], row-stride 12 for b128-friendly, conflict-spread access
  __shared__ float ystep[128 * 12];
  __shared__ float ysl[128 * 12];
  __shared__ float h1t[256 * 12];
  __shared__ float h2t[256 * 12];
  __shared__ float kbuf[6 * 8 * 132];   // k_j for this group's 8 rows, all 128 h
  __shared__ float dxt[32 * 9];         // dX transposed [d][row]
  __shared__ float cbl[256], ccl[256], cdl[256];
  __shared__ float lg[96];
  __shared__ u32 wt[2 * 16 * 516];      // double-buffered bf16-pair weight tile [16 kpairs][<=512 cols]

  const int t   = threadIdx.x;
  const int wg  = blockIdx.x;
  const int bt  = wg >> 3;   // batch group 0..31
  const int hs  = wg & 7;    // h slice 0..7
  const int b0r = bt * 8;

  const float bias0  = b0g[t];
  const float bias1  = b1g[t];
  const int   c2     = 2 * t;                       // this thread's GEMM3 slice cols
  const float bias2a = b2g[hs * 512 + c2];
  const float bias2b = b2g[hs * 512 + c2 + 1];
  const int   kq = t & 3;                           // staging chunk coords
  const int   c0 = t >> 2;

  // ---- y0 = x0 @ l1w^T + l1b ----
  for (int e = 0; e < 4; ++e) {
    int flat = t + 256 * e;
    int h = flat >> 3, r = flat & 7;
    float acc = l1b[h];
    const float* xr = x0g + (size_t)(b0r + r) * 32;
    const float* wr = l1w + h * 32;
#pragma unroll
    for (int d = 0; d < 32; ++d) acc = fmaf(xr[d], wr[d], acc);
    ystep[h * 12 + r] = acc;
  }

  u32 tag = 0;

  for (int step = 0; step < NSTEPS; ++step) {
    const float hh = ts[step + 1] - ts[step];
    __syncthreads();
    {  // coeff slices for this interval
      int r = t >> 5, d = t & 31;
      size_t gi = ((size_t)(b0r + r) * 511 + step) * 32 + d;
      cbl[t] = cbg[gi];
      ccl[t] = ccg[gi];
      cdl[t] = cdg[gi];
    }
    __syncthreads();

    for (int s = 0; s < 6; ++s) {
      {  // dX at frac = C[s]*h : dxt[d][r]
        float fr = CTab[s] * hh;
        int d = t >> 3, r = t & 7;
        int ix = r * 32 + d;
        dxt[d * 9 + r] = cbl[ix] + fr * (2.f * ccl[ix] + 3.f * fr * cdl[ix]);
      }
      // y_s = y + h * sum_j A[s][j] k_j
      for (int e = 0; e < 4; ++e) {
        int flat = t + 256 * e;
        int h = flat >> 3, r = flat & 7;
        float v = ystep[h * 12 + r];
        for (int j = 0; j < s; ++j)
          v = fmaf(hh * AT[s][j], kbuf[j * 1056 + r * 132 + h], v);
        ysl[h * 12 + r] = v;
      }
      __syncthreads();

      // ---- GEMM1: h1 = silu(ys @ w0^T + b0), K=128, 256 cols ----
      float acc1[8];
#pragma unroll
      for (int r = 0; r < 8; ++r) acc1[r] = 0.f;
      {
        u32 pf[4][4];
        auto issue = [&](int kb) {
#pragma unroll
          for (int e = 0; e < 4; ++e) {
            const u16* p = w0b + (size_t)(c0 + 64 * e) * 128 + kb * 32 + kq * 8;
            uint4 v = *(const uint4*)p;
            pf[e][0] = v.x; pf[e][1] = v.y; pf[e][2] = v.z; pf[e][3] = v.w;
          }
        };
        auto put = [&](int buf) {
#pragma unroll
          for (int e = 0; e < 4; ++e) {
            u32* wr = &wt[buf * (16 * 516) + (kq * 4) * 516 + (c0 + 64 * e)];
            wr[0] = pf[e][0]; wr[516] = pf[e][1]; wr[1032] = pf[e][2]; wr[1548] = pf[e][3];
          }
        };
        issue(0); put(0);
        for (int kb = 0; kb < 4; ++kb) {
          if (kb < 3) issue(kb + 1);
          __syncthreads();
          const u32* wrow = &wt[(kb & 1) * (16 * 516)];
#pragma unroll
          for (int kk2 = 0; kk2 < 16; ++kk2) {
            u32 u = wrow[kk2 * 516 + t];
            float wlo = blo(u), whi = bhi(u);
            const float* ya = &ysl[(kb * 32 + 2 * kk2) * 12];
            const float* yb = ya + 12;
#pragma unroll
            for (int r = 0; r < 8; ++r) acc1[r] += ya[r] * wlo + yb[r] * whi;
          }
          if (kb < 3) put((kb + 1) & 1);
        }
      }
#pragma unroll
      for (int r = 0; r < 8; ++r) {
        float x = acc1[r] + bias0;
        h1t[t * 12 + r] = x / (1.f + __expf(-x));
      }

      // ---- GEMM2: h2 = silu(h1 @ w1^T + b1), K=256 ----
      float acc2[8];
#pragma unroll
      for (int r = 0; r < 8; ++r) acc2[r] = 0.f;
      {
        u32 pf[4][4];
        auto issue = [&](int kb) {
#pragma unroll
          for (int e = 0; e < 4; ++e) {
            const u16* p = w1b + (size_t)(c0 + 64 * e) * 256 + kb * 32 + kq * 8;
            uint4 v = *(const uint4*)p;
            pf[e][0] = v.x; pf[e][1] = v.y; pf[e][2] = v.z; pf[e][3] = v.w;
          }
        };
        auto put = [&](int buf) {
#pragma unroll
          for (int e = 0; e < 4; ++e) {
            u32* wr = &wt[buf * (16 * 516) + (kq * 4) * 516 + (c0 + 64 * e)];
            wr[0] = pf[e][0]; wr[516] = pf[e][1]; wr[1032] = pf[e][2]; wr[1548] = pf[e][3];
          }
        };
        issue(0); put(0);
        for (int kb = 0; kb < 8; ++kb) {
          if (kb < 7) issue(kb + 1);
          __syncthreads();
          const u32* wrow = &wt[(kb & 1) * (16 * 516)];
#pragma unroll
          for (int kk2 = 0; kk2 < 16; ++kk2) {
            u32 u = wrow[kk2 * 516 + t];
            float wlo = blo(u), whi = bhi(u);
            const float* ya = &h1t[(kb * 32 + 2 * kk2) * 12];
            const float* yb = ya + 12;
#pragma unroll
            for (int r = 0; r < 8; ++r) acc2[r] += ya[r] * wlo + yb[r] * whi;
          }
          if (kb < 7) put((kb + 1) & 1);
        }
      }
#pragma unroll
      for (int r = 0; r < 8; ++r) {
        float x = acc2[r] + bias1;
        h2t[t * 12 + r] = x / (1.f + __expf(-x));
      }

      // ---- GEMM3 slice: A = h2 @ w2^T + b2 -> tanh -> contract with dX ----
      float accA[8], accB[8];
#pragma unroll
      for (int r = 0; r < 8; ++r) { accA[r] = 0.f; accB[r] = 0.f; }
      {
        u32 pf[8][4];
        auto issue = [&](int kb) {
#pragma unroll
          for (int e = 0; e < 8; ++e) {
            const u16* p = w2b + (size_t)(hs * 512 + c0 + 64 * e) * 256 + kb * 32 + kq * 8;
            uint4 v = *(const uint4*)p;
            pf[e][0] = v.x; pf[e][1] = v.y; pf[e][2] = v.z; pf[e][3] = v.w;
          }
        };
        auto put = [&](int buf) {
#pragma unroll
          for (int e = 0; e < 8; ++e) {
            u32* wr = &wt[buf * (16 * 516) + (kq * 4) * 516 + (c0 + 64 * e)];
            wr[0] = pf[e][0]; wr[516] = pf[e][1]; wr[1032] = pf[e][2]; wr[1548] = pf[e][3];
          }
        };
        issue(0); put(0);
        for (int kb = 0; kb < 8; ++kb) {
          if (kb < 7) issue(kb + 1);
          __syncthreads();
          const u32* wrow = &wt[(kb & 1) * (16 * 516)];
#pragma unroll
          for (int kk2 = 0; kk2 < 16; ++kk2) {
            const u32* wp = &wrow[kk2 * 516 + c2];
            u32 ux = wp[0], uy = wp[1];
            float wa0 = blo(ux), wa1 = bhi(ux);
            float wb0 = blo(uy), wb1 = bhi(uy);
            const float* pa = &h2t[(kb * 32 + 2 * kk2) * 12];
            const float* pb = pa + 12;
#pragma unroll
            for (int r = 0; r < 8; ++r) {
              accA[r] += pa[r] * wa0 + pb[r] * wa1;
              accB[r] += pa[r] * wb0 + pb[r] * wb1;
            }
          }
          if (kb < 7) put((kb + 1) & 1);
        }
      }
      // epilogue: tanh, multiply dX, reduce over d (16 lanes x 2 d each)
      {
        float part[8];
        const int dcol = c2 & 31;
#pragma unroll
        for (int r = 0; r < 8; ++r) {
          float vA = tanhf(accA[r] + bias2a);
          float vB = tanhf(accB[r] + bias2b);
          part[r] = vA * dxt[dcol * 9 + r] + vB * dxt[(dcol + 1) * 9 + r];
        }
#pragma unroll
        for (int m = 1; m < 16; m <<= 1) {
#pragma unroll
          for (int r = 0; r < 8; ++r) part[r] += __shfl_xor(part[r], m, 64);
        }
        if ((t & 15) == 0) {
          int hcol = hs * 16 + (t >> 4);
#pragma unroll
          for (int r = 0; r < 8; ++r) {
            float v = part[r];
            kbuf[s * 1056 + r * 132 + hcol] = v;
            __hip_atomic_store(&kg[((size_t)s * 256 + b0r + r) * 128 + hcol], v,
                               __ATOMIC_RELAXED, __HIP_MEMORY_SCOPE_AGENT);
          }
        }
      }

      // ---- exchange k among the 8 WGs of this batch group ----
      ++tag;  // = step*6 + s + 1
      __threadfence();
      __syncthreads();
      if (t == 0)
        __hip_atomic_store(&flags[wg], tag, __ATOMIC_RELEASE, __HIP_MEMORY_SCOPE_AGENT);
      if (t < 64) {
        u32 v = tag;
        u32* fb = flags + bt * 8;
        do {
          if (t < 8) v = __hip_atomic_load(&fb[t], __ATOMIC_ACQUIRE, __HIP_MEMORY_SCOPE_AGENT);
        } while (!__all((int)(v >= tag)));
      }
      __syncthreads();
      for (int e = 0; e < 4; ++e) {
        int flat = t + 256 * e;
        int r = flat >> 7, h = flat & 127;
        kbuf[s * 1056 + r * 132 + h] =
            __hip_atomic_load(&kg[((size_t)s * 256 + b0r + r) * 128 + h],
                              __ATOMIC_RELAXED, __HIP_MEMORY_SCOPE_AGENT);
      }
      __syncthreads();
    }  // stages

    // ---- final combine: y += h * sum_j B[j] k_j ----
    for (int e = 0; e < 4; ++e) {
      int flat = t + 256 * e;
      int h = flat >> 3, r = flat & 7;
      float v = ystep[h * 12 + r];
#pragma unroll
      for (int j = 0; j < 6; ++j)
        v = fmaf(hh * BTab[j], kbuf[j * 1056 + r * 132 + h], v);
      ystep[h * 12 + r] = v;
    }
  }  // steps

  __syncthreads();
  if (hs == 0) {
    if (t < 80) {
      int r = t / 10, c = t - r * 10;
      float acc = l2b[c];
      for (int h = 0; h < 128; ++h)
        acc = fmaf(ystep[h * 12 + r], l2w[c * 128 + h], acc);
      lg[r * 12 + c] = acc;
    }
    __syncthreads();
    if (t < 8) {
      float m = lg[t * 12];
#pragma unroll
      for (int c = 1; c < 10; ++c) m = fmaxf(m, lg[t * 12 + c]);
      float sum = 0.f, ex[10];
#pragma unroll
      for (int c = 0; c < 10; ++c) { ex[c] = __expf(lg[t * 12 + c] - m); sum += ex[c]; }
      float inv = 1.f / sum;
#pragma unroll
      for (int c = 0; c < 10; ++c) outp[(size_t)(b0r + t) * 10 + c] = ex[c] * inv;
    }
  }
}

extern "C" void kernel_launch(void* const* d_in, const int* in_sizes, int n_in,
                              void* d_out, int out_size, void* d_ws, size_t ws_size,
                              hipStream_t stream) {
  (void)in_sizes; (void)n_in; (void)out_size;
  if (ws_size < WS_NEED) return;  // workspace too small -> fail visibly

  const float* ts  = (const float*)d_in[0];
  const float* cd  = (const float*)d_in[1];
  const float* cc  = (const float*)d_in[2];
  const float* cb  = (const float*)d_in[3];
  // d_in[4] = coeff_a (unused by the reference math)
  const float* x0  = (const float*)d_in[5];
  const float* l1w = (const float*)d_in[6];
  const float* l1b = (const float*)d_in[7];
  const float* w0  = (const float*)d_in[8];
  const float* b0  = (const float*)d_in[9];
  const float* w1  = (const float*)d_in[10];
  const float* b1  = (const float*)d_in[11];
  const float* w2  = (const float*)d_in[12];
  const float* b2  = (const float*)d_in[13];
  const float* l2w = (const float*)d_in[14];
  const float* l2b = (const float*)d_in[15];

  char* ws = (char*)d_ws;
  float* kg    = (float*)(ws + K_OFF);
  u32*   flags = (u32*)(ws + FLAGS_OFF);
  u16*   w0b   = (u16*)(ws + W0_OFF);
  u16*   w1b   = (u16*)(ws + W1_OFF);
  u16*   w2b   = (u16*)(ws + W2_OFF);

  hipMemsetAsync(flags, 0, NWG * sizeof(u32), stream);
  cvt_weights<<<4096, 256, 0, stream>>>(w0, w1, w2, w0b, w1b, w2b);
  cde_kernel<<<NWG, NTHR, 0, stream>>>(ts, cd, cc, cb, x0, l1w, l1b,
                                       b0, b1, b2, l2w, l2b,
                                       w0b, w1b, w2b, kg, flags, (float*)d_out);
}

// Round 3
// 78394.299 us; speedup vs baseline: 1.9557x; 1.9557x over previous
//
#include <hip/hip_runtime.h>

typedef unsigned int u32;
typedef unsigned short u16;
typedef __attribute__((ext_vector_type(8))) short bf16x8;
typedef __attribute__((ext_vector_type(4))) float f32x4;
typedef __attribute__((ext_vector_type(4))) u32 u32x4;

static constexpr int NWG    = 256;   // 16 batch-groups x 16 h-slices
static constexpr int NTHR   = 256;
static constexpr int NSTEPS = 511;

// ---- workspace layout (bytes) ----
static constexpr size_t K_OFF     = 0;                         // float kg[6][256][128]
static constexpr size_t FLAGS_OFF = 6ull * 256 * 128 * 4;      // u32 flags[256*32] (128B stride)
static constexpr size_t W0_OFF    = FLAGS_OFF + 256 * 32 * 4;  // u16 w0b[256*128]
static constexpr size_t W1_OFF    = W0_OFF + 256 * 128 * 2;    // u16 w1b[256*256]
static constexpr size_t W2_OFF    = W1_OFF + 256 * 256 * 2;    // u16 w2b[4096*256]
static constexpr size_t WS_NEED   = W2_OFF + 4096ull * 256 * 2;

// ---- Tsit5 tableau (zero-padded A for static 6-wide sums) ----
__device__ static const float AT6[6][6] = {
  {0.f, 0.f, 0.f, 0.f, 0.f, 0.f},
  {0.161f, 0.f, 0.f, 0.f, 0.f, 0.f},
  {-0.008480655492356989f, 0.335480655492357f, 0.f, 0.f, 0.f, 0.f},
  {2.8971530571054935f, -6.359448489975075f, 4.3622954328695815f, 0.f, 0.f, 0.f},
  {5.325864828439257f, -11.748883564062828f, 7.4955393428898365f, -0.09249506636175525f, 0.f, 0.f},
  {5.86145544294642f, -12.92096931784711f, 8.159367898576159f, -0.071584973281401f, -0.028269050394068383f, 0.f}
};
__device__ static const float BT6[6] = {
  0.09646076681806523f, 0.01f, 0.4798896504144996f, 1.379008574103742f,
  -3.290069515436081f, 2.324710524099774f
};
__device__ static const float CT6[6] = {0.f, 0.161f, 0.327f, 0.9f, 0.9800255409045097f, 1.f};

__device__ __forceinline__ u16 cvbf(float f) {  // fp32 -> bf16 RNE
  u32 u = __float_as_uint(f);
  return (u16)((u + 0x7fffu + ((u >> 16) & 1u)) >> 16);
}
__device__ __forceinline__ float fsilu(float x) { return x / (1.f + __expf(-x)); }
__device__ __forceinline__ float ftanh(float x) {
  float e = __expf(2.f * x);
  return 1.f - 2.f / (e + 1.f);
}
__device__ __forceinline__ f32x4 MF(bf16x8 a, bf16x8 b, f32x4 c) {
  return __builtin_amdgcn_mfma_f32_16x16x32_bf16(a, b, c, 0, 0, 0);
}

// fp32 -> bf16 weights
__global__ void cvt_weights(const float* __restrict__ w0, const float* __restrict__ w1,
                            const float* __restrict__ w2, u16* __restrict__ o0,
                            u16* __restrict__ o1, u16* __restrict__ o2) {
  int i = blockIdx.x * blockDim.x + threadIdx.x;
  if (i < 256 * 128)  o0[i] = cvbf(w0[i]);
  if (i < 256 * 256)  o1[i] = cvbf(w1[i]);
  if (i < 4096 * 256) o2[i] = cvbf(w2[i]);
}

// Persistent MFMA kernel. WG = (batch-group g: 16 rows) x (h-slice hs: 256 of 4096 cols).
// W0/W1 B-frags persistent in VGPRs; W2 slice persistent in LDS (frag-linear layout).
// One cross-WG k-exchange per stage among the 16 WGs of a group.
__launch_bounds__(NTHR, 1)
__global__ void cde_kernel(const float* __restrict__ ts,
                           const float* __restrict__ cdg, const float* __restrict__ ccg,
                           const float* __restrict__ cbg,
                           const float* __restrict__ x0g, const float* __restrict__ l1w,
                           const float* __restrict__ l1b,
                           const float* __restrict__ b0g, const float* __restrict__ b1g,
                           const float* __restrict__ b2g,
                           const float* __restrict__ l2w, const float* __restrict__ l2b,
                           const u16* __restrict__ w0b, const u16* __restrict__ w1b,
                           const u16* __restrict__ w2b,
                           float* kg, u32* flags, float* __restrict__ outp) {
  __shared__ u32 w2l[32768];      // 128KB: W2 frags [ks(8)][gct(16)][lane(64)][4 u32]
  __shared__ u16 ysl[16 * 128];   // 4KB  [row][128] bf16, XOR-swz
  __shared__ u16 h1l[16 * 256];   // 8KB  [row][256] bf16, XOR-swz
  __shared__ u16 h2l[16 * 256];   // 8KB
  __shared__ float dxt[32 * 17];  // dX [d][row], pad 17
  __shared__ float lg[192];       // head logits

  const int t  = threadIdx.x;
  const int wg = blockIdx.x;
  const int g  = wg >> 4;    // batch group 0..15
  const int hs = wg & 15;    // h slice 0..15
  const int b0r = g * 16;
  const int wv = t >> 6, l = t & 63, lr = l & 15, lk = l >> 4;
  const int row_o = t & 15;          // owned row for ys/k/ystep
  const int hb    = (t >> 4) * 8;    // owned h-range base

  // ---- persistent weight fragments ----
  bf16x8 w0f[4][4], w1f[4][8];
  float bias0v[4], bias1v[4], bias2v[4];
#pragma unroll
  for (int ct = 0; ct < 4; ++ct) {
    const int col = wv * 64 + ct * 16 + lr;
    bias0v[ct] = b0g[col];
    bias1v[ct] = b1g[col];
    bias2v[ct] = b2g[hs * 256 + col];
    const u16* base0 = w0b + (size_t)col * 128 + lk * 8;
#pragma unroll
    for (int ks = 0; ks < 4; ++ks) w0f[ct][ks] = *(const bf16x8*)(base0 + ks * 32);
    const u16* base1 = w1b + (size_t)col * 256 + lk * 8;
#pragma unroll
    for (int ks = 0; ks < 8; ++ks) w1f[ct][ks] = *(const bf16x8*)(base1 + ks * 32);
    const u16* base2 = w2b + (size_t)(hs * 256 + col) * 256 + lk * 8;
#pragma unroll
    for (int ks = 0; ks < 8; ++ks) {   // each thread writes its own future read slots
      u32x4 v = *(const u32x4*)(base2 + ks * 32);
      *(u32x4*)&w2l[(size_t)((ks * 16 + wv * 4 + ct) * 64 + l) * 4] = v;
    }
  }

  // ---- y0 = x0 @ l1w^T + l1b (owned 8 elems) ----
  float yv[8];
  {
    const float* xr = x0g + (size_t)(b0r + row_o) * 32;
#pragma unroll
    for (int e = 0; e < 8; ++e) {
      float acc = l1b[hb + e];
      const float* wr = l1w + (size_t)(hb + e) * 32;
#pragma unroll
      for (int d = 0; d < 32; ++d) acc = fmaf(xr[d], wr[d], acc);
      yv[e] = acc;
    }
  }

  float kk[6][8];
#pragma unroll
  for (int j = 0; j < 6; ++j)
#pragma unroll
    for (int e = 0; e < 8; ++e) kk[j][e] = 0.f;

  // coeff prefetch (thread's 2 dxt elems: row=t>>4, d=2*(t&15)+e)
  float pcb[2], pcc[2], pcd[2];
  auto ld_coeff = [&](int st) {
    size_t gi = ((size_t)(b0r + (t >> 4)) * 511 + st) * 32 + 2 * (t & 15);
    float2 vb = *(const float2*)(cbg + gi); pcb[0] = vb.x; pcb[1] = vb.y;
    float2 vc = *(const float2*)(ccg + gi); pcc[0] = vc.x; pcc[1] = vc.y;
    float2 vd = *(const float2*)(cdg + gi); pcd[0] = vd.x; pcd[1] = vd.y;
  };
  ld_coeff(0);
  float hh_next = ts[1] - ts[0];
  u32 tag = 0;
  __syncthreads();

  for (int step = 0; step < NSTEPS; ++step) {
    const float hh = hh_next;
    const float cbv0 = pcb[0], cbv1 = pcb[1];
    const float ccv0 = pcc[0], ccv1 = pcc[1];
    const float cdv0 = pcd[0], cdv1 = pcd[1];
    if (step + 1 < NSTEPS) { ld_coeff(step + 1); hh_next = ts[step + 2] - ts[step + 1]; }

    for (int s = 0; s < 6; ++s) {
      // ---- dxt + ys (register combine -> bf16 -> swizzled LDS) ----
      const float fr = CT6[s] * hh;
      {
        int d0 = 2 * (t & 15);
        dxt[d0 * 17 + (t >> 4)]       = cbv0 + fr * (2.f * ccv0 + 3.f * fr * cdv0);
        dxt[(d0 + 1) * 17 + (t >> 4)] = cbv1 + fr * (2.f * ccv1 + 3.f * fr * cdv1);
      }
      const float a0 = hh * AT6[s][0], a1 = hh * AT6[s][1], a2 = hh * AT6[s][2];
      const float a3 = hh * AT6[s][3], a4 = hh * AT6[s][4], a5 = hh * AT6[s][5];
      {
        u32 yp[4];
#pragma unroll
        for (int e2 = 0; e2 < 4; ++e2) {
          float v0 = yv[2 * e2], v1 = yv[2 * e2 + 1];
          v0 = fmaf(a0, kk[0][2 * e2], v0); v1 = fmaf(a0, kk[0][2 * e2 + 1], v1);
          v0 = fmaf(a1, kk[1][2 * e2], v0); v1 = fmaf(a1, kk[1][2 * e2 + 1], v1);
          v0 = fmaf(a2, kk[2][2 * e2], v0); v1 = fmaf(a2, kk[2][2 * e2 + 1], v1);
          v0 = fmaf(a3, kk[3][2 * e2], v0); v1 = fmaf(a3, kk[3][2 * e2 + 1], v1);
          v0 = fmaf(a4, kk[4][2 * e2], v0); v1 = fmaf(a4, kk[4][2 * e2 + 1], v1);
          v0 = fmaf(a5, kk[5][2 * e2], v0); v1 = fmaf(a5, kk[5][2 * e2 + 1], v1);
          yp[e2] = (u32)cvbf(v0) | ((u32)cvbf(v1) << 16);
        }
        int boff = row_o * 256 + (((t >> 4) * 16) ^ ((row_o & 7) << 4));
        u32x4 w; w[0] = yp[0]; w[1] = yp[1]; w[2] = yp[2]; w[3] = yp[3];
        *(u32x4*)((char*)ysl + boff) = w;
      }
      __syncthreads();

      // ---- GEMM1: h1 = silu(ys @ w0^T + b0), K=128 ----
      f32x4 acc[4];
#pragma unroll
      for (int ct = 0; ct < 4; ++ct) acc[ct] = f32x4{0.f, 0.f, 0.f, 0.f};
#pragma unroll
      for (int ks = 0; ks < 4; ++ks) {
        bf16x8 af = *(const bf16x8*)((char*)ysl + lr * 256 + ((ks * 64 + lk * 16) ^ ((lr & 7) << 4)));
#pragma unroll
        for (int ct = 0; ct < 4; ++ct) acc[ct] = MF(af, w0f[ct][ks], acc[ct]);
      }
#pragma unroll
      for (int ct = 0; ct < 4; ++ct) {
        int col = wv * 64 + ct * 16 + lr;
#pragma unroll
        for (int r = 0; r < 4; ++r) {
          int row = lk * 4 + r;
          *(u16*)((char*)h1l + row * 512 + ((col * 2) ^ ((row & 7) << 4))) =
              cvbf(fsilu(acc[ct][r] + bias0v[ct]));
        }
      }
      __syncthreads();

      // ---- GEMM2: h2 = silu(h1 @ w1^T + b1), K=256 ----
#pragma unroll
      for (int ct = 0; ct < 4; ++ct) acc[ct] = f32x4{0.f, 0.f, 0.f, 0.f};
#pragma unroll
      for (int ks = 0; ks < 8; ++ks) {
        bf16x8 af = *(const bf16x8*)((char*)h1l + lr * 512 + ((ks * 64 + lk * 16) ^ ((lr & 7) << 4)));
#pragma unroll
        for (int ct = 0; ct < 4; ++ct) acc[ct] = MF(af, w1f[ct][ks], acc[ct]);
      }
#pragma unroll
      for (int ct = 0; ct < 4; ++ct) {
        int col = wv * 64 + ct * 16 + lr;
#pragma unroll
        for (int r = 0; r < 4; ++r) {
          int row = lk * 4 + r;
          *(u16*)((char*)h2l + row * 512 + ((col * 2) ^ ((row & 7) << 4))) =
              cvbf(fsilu(acc[ct][r] + bias1v[ct]));
        }
      }
      __syncthreads();

      // ---- GEMM3 slice + tanh + dX-contract -> k ----
#pragma unroll
      for (int ct = 0; ct < 4; ++ct) acc[ct] = f32x4{0.f, 0.f, 0.f, 0.f};
#pragma unroll
      for (int ks = 0; ks < 8; ++ks) {
        bf16x8 af = *(const bf16x8*)((char*)h2l + lr * 512 + ((ks * 64 + lk * 16) ^ ((lr & 7) << 4)));
#pragma unroll
        for (int ct = 0; ct < 4; ++ct) {
          bf16x8 bf = *(const bf16x8*)&w2l[(size_t)((ks * 16 + wv * 4 + ct) * 64 + l) * 4];
          acc[ct] = MF(af, bf, acc[ct]);
        }
      }
      {
        float s01[4], s23[4];
#pragma unroll
        for (int r = 0; r < 4; ++r) {
          int row = lk * 4 + r;
          float v0 = ftanh(acc[0][r] + bias2v[0]) * dxt[lr * 17 + row];
          float v1 = ftanh(acc[1][r] + bias2v[1]) * dxt[(16 + lr) * 17 + row];
          s01[r] = v0 + v1;
          float v2 = ftanh(acc[2][r] + bias2v[2]) * dxt[lr * 17 + row];
          float v3 = ftanh(acc[3][r] + bias2v[3]) * dxt[(16 + lr) * 17 + row];
          s23[r] = v2 + v3;
        }
#pragma unroll
        for (int m = 1; m < 16; m <<= 1) {
#pragma unroll
          for (int r = 0; r < 4; ++r) {
            s01[r] += __shfl_xor(s01[r], m, 64);
            s23[r] += __shfl_xor(s23[r], m, 64);
          }
        }
        if (lr == 0) {
          int h0 = hs * 8 + wv * 2;
#pragma unroll
          for (int r = 0; r < 4; ++r) {
            int grow = b0r + lk * 4 + r;
            __hip_atomic_store(&kg[((size_t)s * 256 + grow) * 128 + h0], s01[r],
                               __ATOMIC_RELAXED, __HIP_MEMORY_SCOPE_AGENT);
            __hip_atomic_store(&kg[((size_t)s * 256 + grow) * 128 + h0 + 1], s23[r],
                               __ATOMIC_RELAXED, __HIP_MEMORY_SCOPE_AGENT);
          }
        }
      }

      // ---- exchange among the 16 WGs of this group ----
      ++tag;
      __threadfence();
      __syncthreads();
      if (t == 0)
        __hip_atomic_store(&flags[wg * 32], tag, __ATOMIC_RELEASE, __HIP_MEMORY_SCOPE_AGENT);
      if (t < 64) {
        u32 v = tag;
        u32* fb = flags + g * 16 * 32;
        do {
          if (t < 16) v = __hip_atomic_load(&fb[t * 32], __ATOMIC_RELAXED, __HIP_MEMORY_SCOPE_AGENT);
        } while (!__all((int)(v >= tag)));
        __builtin_amdgcn_fence(__ATOMIC_ACQUIRE, "agent");
      }
      __syncthreads();
      {
        float kv[8];
        float* src = kg + ((size_t)s * 256 + b0r + row_o) * 128 + hb;
#pragma unroll
        for (int e = 0; e < 8; ++e)
          kv[e] = __hip_atomic_load(&src[e], __ATOMIC_RELAXED, __HIP_MEMORY_SCOPE_AGENT);
        switch (s) {
          case 0: { for (int e = 0; e < 8; ++e) kk[0][e] = kv[e]; break; }
          case 1: { for (int e = 0; e < 8; ++e) kk[1][e] = kv[e]; break; }
          case 2: { for (int e = 0; e < 8; ++e) kk[2][e] = kv[e]; break; }
          case 3: { for (int e = 0; e < 8; ++e) kk[3][e] = kv[e]; break; }
          case 4: { for (int e = 0; e < 8; ++e) kk[4][e] = kv[e]; break; }
          default: { for (int e = 0; e < 8; ++e) kk[5][e] = kv[e]; break; }
        }
      }
    }  // stages

    // ---- y += h * sum_j B[j] k_j (pure registers) ----
    const float c0 = hh * BT6[0], c1 = hh * BT6[1], c2 = hh * BT6[2];
    const float c3 = hh * BT6[3], c4 = hh * BT6[4], c5 = hh * BT6[5];
#pragma unroll
    for (int e = 0; e < 8; ++e) {
      float v = yv[e];
      v = fmaf(c0, kk[0][e], v); v = fmaf(c1, kk[1][e], v); v = fmaf(c2, kk[2][e], v);
      v = fmaf(c3, kk[3][e], v); v = fmaf(c4, kk[4][e], v); v = fmaf(c5, kk[5][e], v);
      yv[e] = v;
    }
  }  // steps

  // ---- head: softmax(y @ l2w^T + l2b) for this group's 16 rows ----
  __syncthreads();
  if (hs == 0) {
    float* yh = (float*)w2l;  // W2 LDS no longer needed
#pragma unroll
    for (int e = 0; e < 8; ++e) yh[row_o * 132 + hb + e] = yv[e];
    __syncthreads();
    if (t < 160) {
      int r = t / 10, c = t - r * 10;
      float acc = l2b[c];
      const float* wr = l2w + (size_t)c * 128;
      for (int h2 = 0; h2 < 128; ++h2) acc = fmaf(yh[r * 132 + h2], wr[h2], acc);
      lg[r * 12 + c] = acc;
    }
    __syncthreads();
    if (t < 16) {
      float m = lg[t * 12];
#pragma unroll
      for (int c = 1; c < 10; ++c) m = fmaxf(m, lg[t * 12 + c]);
      float sum = 0.f, ex[10];
#pragma unroll
      for (int c = 0; c < 10; ++c) { ex[c] = __expf(lg[t * 12 + c] - m); sum += ex[c]; }
      float inv = 1.f / sum;
#pragma unroll
      for (int c = 0; c < 10; ++c) outp[(size_t)(b0r + t) * 10 + c] = ex[c] * inv;
    }
  }
}

extern "C" void kernel_launch(void* const* d_in, const int* in_sizes, int n_in,
                              void* d_out, int out_size, void* d_ws, size_t ws_size,
                              hipStream_t stream) {
  (void)in_sizes; (void)n_in; (void)out_size;
  if (ws_size < WS_NEED) return;

  const float* ts  = (const float*)d_in[0];
  const float* cd  = (const float*)d_in[1];
  const float* cc  = (const float*)d_in[2];
  const float* cb  = (const float*)d_in[3];
  // d_in[4] = coeff_a (unused by the reference math)
  const float* x0  = (const float*)d_in[5];
  const float* l1w = (const float*)d_in[6];
  const float* l1b = (const float*)d_in[7];
  const float* w0  = (const float*)d_in[8];
  const float* b0  = (const float*)d_in[9];
  const float* w1  = (const float*)d_in[10];
  const float* b1  = (const float*)d_in[11];
  const float* w2  = (const float*)d_in[12];
  const float* b2  = (const float*)d_in[13];
  const float* l2w = (const float*)d_in[14];
  const float* l2b = (const float*)d_in[15];

  char* ws = (char*)d_ws;
  float* kg    = (float*)(ws + K_OFF);
  u32*   flags = (u32*)(ws + FLAGS_OFF);
  u16*   w0b   = (u16*)(ws + W0_OFF);
  u16*   w1b   = (u16*)(ws + W1_OFF);
  u16*   w2b   = (u16*)(ws + W2_OFF);

  (void)hipMemsetAsync(flags, 0, 256 * 32 * sizeof(u32), stream);
  cvt_weights<<<4096, 256, 0, stream>>>(w0, w1, w2, w0b, w1b, w2b);
  cde_kernel<<<NWG, NTHR, 0, stream>>>(ts, cd, cc, cb, x0, l1w, l1b,
                                       b0, b1, b2, l2w, l2b,
                                       w0b, w1b, w2b, kg, flags, (float*)d_out);
}

// Round 4
// 42416.510 us; speedup vs baseline: 3.6145x; 1.8482x over previous
//
#include <hip/hip_runtime.h>

typedef unsigned int u32;
typedef unsigned long long u64;
typedef unsigned short u16;
typedef __attribute__((ext_vector_type(8))) short bf16x8;
typedef __attribute__((ext_vector_type(4))) float f32x4;
typedef __attribute__((ext_vector_type(4))) u32 u32x4;

static constexpr int NWG    = 128;   // 8 pair-groups x 16 h-slices
static constexpr int NTHR   = 256;
static constexpr int NSTEPS = 511;

// ---- workspace layout (bytes) ----
// kg: u32 kg[6][8][2][16][64]  (stage, pair-group, sub, h-slice, row*4+hpair) packed bf16x2
static constexpr size_t K_OFF    = 0;
static constexpr size_t KG_U32   = 6ull * 8 * 2 * 16 * 64;        // 98304 u32
static constexpr size_t CNT_OFF  = KG_U32 * 4;                    // 393216
static constexpr size_t W0_OFF   = CNT_OFF + 16 * 256;            // 16 counters, 256B apart
static constexpr size_t W1_OFF   = W0_OFF + 256 * 128 * 2;
static constexpr size_t W2_OFF   = W1_OFF + 256 * 256 * 2;
static constexpr size_t WS_NEED  = W2_OFF + 4096ull * 256 * 2;    // ~2.57 MB

__device__ static const float AT6[6][6] = {
  {0.f, 0.f, 0.f, 0.f, 0.f, 0.f},
  {0.161f, 0.f, 0.f, 0.f, 0.f, 0.f},
  {-0.008480655492356989f, 0.335480655492357f, 0.f, 0.f, 0.f, 0.f},
  {2.8971530571054935f, -6.359448489975075f, 4.3622954328695815f, 0.f, 0.f, 0.f},
  {5.325864828439257f, -11.748883564062828f, 7.4955393428898365f, -0.09249506636175525f, 0.f, 0.f},
  {5.86145544294642f, -12.92096931784711f, 8.159367898576159f, -0.071584973281401f, -0.028269050394068383f, 0.f}
};
__device__ static const float BT6[6] = {
  0.09646076681806523f, 0.01f, 0.4798896504144996f, 1.379008574103742f,
  -3.290069515436081f, 2.324710524099774f
};
__device__ static const float CT6[6] = {0.f, 0.161f, 0.327f, 0.9f, 0.9800255409045097f, 1.f};

__device__ __forceinline__ u16 cvbf(float f) {
  u32 u = __float_as_uint(f);
  return (u16)((u + 0x7fffu + ((u >> 16) & 1u)) >> 16);
}
__device__ __forceinline__ float blo(u32 u) { return __uint_as_float(u << 16); }
__device__ __forceinline__ float bhi(u32 u) { return __uint_as_float(u & 0xffff0000u); }
__device__ __forceinline__ float fsilu(float x) { return x / (1.f + __expf(-x)); }
__device__ __forceinline__ float ftanh(float x) {
  float e = __expf(2.f * x);
  return 1.f - 2.f / (e + 1.f);
}
__device__ __forceinline__ f32x4 MF(bf16x8 a, bf16x8 b, f32x4 c) {
  return __builtin_amdgcn_mfma_f32_16x16x32_bf16(a, b, c, 0, 0, 0);
}

__global__ void cvt_weights(const float* __restrict__ w0, const float* __restrict__ w1,
                            const float* __restrict__ w2, u16* __restrict__ o0,
                            u16* __restrict__ o1, u16* __restrict__ o2) {
  int i = blockIdx.x * blockDim.x + threadIdx.x;
  if (i < 256 * 128)  o0[i] = cvbf(w0[i]);
  if (i < 256 * 256)  o1[i] = cvbf(w1[i]);
  if (i < 4096 * 256) o2[i] = cvbf(w2[i]);
}

// Persistent MFMA kernel, dual-subgroup interleave for exchange-latency hiding.
// WG = (pair-group pg: 32 rows as subs A/B of 16) x (h-slice hs: 256 GEMM3 cols).
__launch_bounds__(NTHR, 1)
__global__ void cde_kernel(const float* __restrict__ ts,
                           const float* __restrict__ cdg, const float* __restrict__ ccg,
                           const float* __restrict__ cbg,
                           const float* __restrict__ x0g, const float* __restrict__ l1w,
                           const float* __restrict__ l1b,
                           const float* __restrict__ b0g, const float* __restrict__ b1g,
                           const float* __restrict__ b2g,
                           const float* __restrict__ l2w, const float* __restrict__ l2b,
                           const u16* __restrict__ w0b, const u16* __restrict__ w1b,
                           const u16* __restrict__ w2b,
                           u32* kg, u32* cnt, float* __restrict__ outp) {
  __shared__ u32 w2l[32768];                              // 128KB W2 frags
  __shared__ u16 ysl[16 * 128];                           // 4KB
  __shared__ u16 h1l[16 * 256];                           // 8KB
  __shared__ u16 h2l[16 * 256];                           // 8KB
  __shared__ float dxt[32 * 17];                          // 2.1KB (aliased as head logits)
  __shared__ u32 kex[1024] __attribute__((aligned(16)));  // 4KB gather/stage buffer

  const int t  = threadIdx.x;
  const int wg = blockIdx.x;
  const int pg = wg >> 4;    // pair-group 0..7 (32 rows)
  const int hs = wg & 15;    // h slice 0..15
  const int b0r = pg * 32;
  const int wv = t >> 6, l = t & 63, lr = l & 15, lk = l >> 4;
  const int row_o = t & 15;
  const int hb    = (t >> 4) * 8;

  // ---- persistent weight fragments (proven R3 layout) ----
  bf16x8 w0f[4][4], w1f[4][8];
  float bias0v[4], bias1v[4], bias2v[4];
#pragma unroll
  for (int ct = 0; ct < 4; ++ct) {
    const int col = wv * 64 + ct * 16 + lr;
    bias0v[ct] = b0g[col];
    bias1v[ct] = b1g[col];
    bias2v[ct] = b2g[hs * 256 + col];
    const u16* base0 = w0b + (size_t)col * 128 + lk * 8;
#pragma unroll
    for (int ks = 0; ks < 4; ++ks) w0f[ct][ks] = *(const bf16x8*)(base0 + ks * 32);
    const u16* base1 = w1b + (size_t)col * 256 + lk * 8;
#pragma unroll
    for (int ks = 0; ks < 8; ++ks) w1f[ct][ks] = *(const bf16x8*)(base1 + ks * 32);
    const u16* base2 = w2b + (size_t)(hs * 256 + col) * 256 + lk * 8;
#pragma unroll
    for (int ks = 0; ks < 8; ++ks) {
      u32x4 v = *(const u32x4*)(base2 + ks * 32);
      *(u32x4*)&w2l[(size_t)((ks * 16 + wv * 4 + ct) * 64 + l) * 4] = v;
    }
  }

  // ---- per-sub state ----
  float yvA[8], yvB[8];
  u32 kkA[6][4], kkB[6][4];
#pragma unroll
  for (int j = 0; j < 6; ++j)
#pragma unroll
    for (int p = 0; p < 4; ++p) { kkA[j][p] = 0u; kkB[j][p] = 0u; }

  auto initY = [&](int sub, float (&yv)[8]) {
    const float* xr = x0g + (size_t)(b0r + sub * 16 + row_o) * 32;
#pragma unroll
    for (int e = 0; e < 8; ++e) {
      float acc = l1b[hb + e];
      const float* wr = l1w + (size_t)(hb + e) * 32;
#pragma unroll
      for (int d = 0; d < 32; ++d) acc = fmaf(xr[d], wr[d], acc);
      yv[e] = acc;
    }
  };
  initY(0, yvA);
  initY(1, yvB);

  float pcbA[2], pccA[2], pcdA[2], pcbB[2], pccB[2], pcdB[2];
  auto ld_coeff = [&](int st, int sub, float (&pb)[2], float (&pc)[2], float (&pd)[2]) {
    size_t gi = ((size_t)(b0r + sub * 16 + (t >> 4)) * 511 + st) * 32 + 2 * (t & 15);
    float2 vb = *(const float2*)(cbg + gi); pb[0] = vb.x; pb[1] = vb.y;
    float2 vc = *(const float2*)(ccg + gi); pc[0] = vc.x; pc[1] = vc.y;
    float2 vd = *(const float2*)(cdg + gi); pd[0] = vd.x; pd[1] = vd.y;
  };
  ld_coeff(0, 0, pcbA, pccA, pcdA);
  ld_coeff(0, 1, pcbB, pccB, pcdB);
  float hh_next = ts[1] - ts[0];
  __syncthreads();

  // ---- one full stage for one sub: combine ys -> GEMMs -> k slice -> post ----
  auto run_stage = [&](int s, float hh, const float (&c6)[6], float (&yv)[8],
                       u32 (&kkp)[6][4], int sub) {
    const float fr = CT6[s] * hh;
    {
      int d0 = 2 * (t & 15), rl = t >> 4;
      dxt[d0 * 17 + rl]       = c6[0] + fr * (2.f * c6[2] + 3.f * fr * c6[4]);
      dxt[(d0 + 1) * 17 + rl] = c6[1] + fr * (2.f * c6[3] + 3.f * fr * c6[5]);
    }
    float a[6];
#pragma unroll
    for (int j = 0; j < 6; ++j) a[j] = hh * AT6[s][j];
    {
      u32 yp[4];
#pragma unroll
      for (int p = 0; p < 4; ++p) {
        float v0 = yv[2 * p], v1 = yv[2 * p + 1];
#pragma unroll
        for (int j = 0; j < 6; ++j) {
          v0 = fmaf(a[j], blo(kkp[j][p]), v0);
          v1 = fmaf(a[j], bhi(kkp[j][p]), v1);
        }
        yp[p] = (u32)cvbf(v0) | ((u32)cvbf(v1) << 16);
      }
      int boff = row_o * 256 + (((t >> 4) * 16) ^ ((row_o & 7) << 4));
      u32x4 w; w[0] = yp[0]; w[1] = yp[1]; w[2] = yp[2]; w[3] = yp[3];
      *(u32x4*)((char*)ysl + boff) = w;
    }
    __syncthreads();

    // GEMM1
    f32x4 acc[4];
#pragma unroll
    for (int ct = 0; ct < 4; ++ct) acc[ct] = f32x4{0.f, 0.f, 0.f, 0.f};
#pragma unroll
    for (int ks = 0; ks < 4; ++ks) {
      bf16x8 af = *(const bf16x8*)((char*)ysl + lr * 256 + ((ks * 64 + lk * 16) ^ ((lr & 7) << 4)));
#pragma unroll
      for (int ct = 0; ct < 4; ++ct) acc[ct] = MF(af, w0f[ct][ks], acc[ct]);
    }
#pragma unroll
    for (int ct = 0; ct < 4; ++ct) {
      int col = wv * 64 + ct * 16 + lr;
#pragma unroll
      for (int r = 0; r < 4; ++r) {
        int row = lk * 4 + r;
        *(u16*)((char*)h1l + row * 512 + ((col * 2) ^ ((row & 7) << 4))) =
            cvbf(fsilu(acc[ct][r] + bias0v[ct]));
      }
    }
    __syncthreads();

    // GEMM2
#pragma unroll
    for (int ct = 0; ct < 4; ++ct) acc[ct] = f32x4{0.f, 0.f, 0.f, 0.f};
#pragma unroll
    for (int ks = 0; ks < 8; ++ks) {
      bf16x8 af = *(const bf16x8*)((char*)h1l + lr * 512 + ((ks * 64 + lk * 16) ^ ((lr & 7) << 4)));
#pragma unroll
      for (int ct = 0; ct < 4; ++ct) acc[ct] = MF(af, w1f[ct][ks], acc[ct]);
    }
#pragma unroll
    for (int ct = 0; ct < 4; ++ct) {
      int col = wv * 64 + ct * 16 + lr;
#pragma unroll
      for (int r = 0; r < 4; ++r) {
        int row = lk * 4 + r;
        *(u16*)((char*)h2l + row * 512 + ((col * 2) ^ ((row & 7) << 4))) =
            cvbf(fsilu(acc[ct][r] + bias1v[ct]));
      }
    }
    __syncthreads();

    // GEMM3 + tanh + dX contract
#pragma unroll
    for (int ct = 0; ct < 4; ++ct) acc[ct] = f32x4{0.f, 0.f, 0.f, 0.f};
#pragma unroll
    for (int ks = 0; ks < 8; ++ks) {
      bf16x8 af = *(const bf16x8*)((char*)h2l + lr * 512 + ((ks * 64 + lk * 16) ^ ((lr & 7) << 4)));
#pragma unroll
      for (int ct = 0; ct < 4; ++ct) {
        bf16x8 bf = *(const bf16x8*)&w2l[(size_t)((ks * 16 + wv * 4 + ct) * 64 + l) * 4];
        acc[ct] = MF(af, bf, acc[ct]);
      }
    }
    {
      float s01[4], s23[4];
#pragma unroll
      for (int r = 0; r < 4; ++r) {
        int row = lk * 4 + r;
        float v0 = ftanh(acc[0][r] + bias2v[0]) * dxt[lr * 17 + row];
        float v1 = ftanh(acc[1][r] + bias2v[1]) * dxt[(16 + lr) * 17 + row];
        s01[r] = v0 + v1;
        float v2 = ftanh(acc[2][r] + bias2v[2]) * dxt[lr * 17 + row];
        float v3 = ftanh(acc[3][r] + bias2v[3]) * dxt[(16 + lr) * 17 + row];
        s23[r] = v2 + v3;
      }
#pragma unroll
      for (int m = 1; m < 16; m <<= 1) {
#pragma unroll
        for (int r = 0; r < 4; ++r) {
          s01[r] += __shfl_xor(s01[r], m, 64);
          s23[r] += __shfl_xor(s23[r], m, 64);
        }
      }
      if (lr == 0) {
#pragma unroll
        for (int r = 0; r < 4; ++r)
          kex[(lk * 4 + r) * 4 + wv] = (u32)cvbf(s01[r]) | ((u32)cvbf(s23[r]) << 16);
      }
    }
    __syncthreads();
    // coalesced 256B bypass store of this WG's slice, then arrive
    const size_t slabBase = ((((size_t)s * 8 + pg) * 2 + sub) * 16 + hs) * 64;
    if (t < 64)
      __hip_atomic_store(&kg[slabBase + t], kex[t], __ATOMIC_RELAXED, __HIP_MEMORY_SCOPE_AGENT);
    asm volatile("s_waitcnt vmcnt(0)" ::: "memory");
    __syncthreads();
    if (t == 0)
      __hip_atomic_fetch_add(cnt + (pg * 2 + sub) * 64, 1u,
                             __ATOMIC_RELAXED, __HIP_MEMORY_SCOPE_AGENT);
  };

  // ---- wait + cooperative coalesced gather of one stage's full k for one sub ----
  auto gather = [&](int sdone, int sub, u32 (&kkp)[6][4], u32 target) {
    if (t == 0) {
      const u32* c = cnt + (pg * 2 + sub) * 64;
      while ((int)(__hip_atomic_load(c, __ATOMIC_RELAXED, __HIP_MEMORY_SCOPE_AGENT) - target) < 0)
        __builtin_amdgcn_s_sleep(1);
    }
    __syncthreads();
    const u64* s64 = (const u64*)(kg + (((size_t)sdone * 8 + pg) * 2 + sub) * 16 * 64);
    u64 v0 = __hip_atomic_load(&s64[t],       __ATOMIC_RELAXED, __HIP_MEMORY_SCOPE_AGENT);
    u64 v1 = __hip_atomic_load(&s64[t + 256], __ATOMIC_RELAXED, __HIP_MEMORY_SCOPE_AGENT);
    u64* k64 = (u64*)kex;
    k64[t] = v0; k64[t + 256] = v1;
    __syncthreads();
    u32x4 kr = *(const u32x4*)&kex[(t >> 4) * 64 + (t & 15) * 4];
    switch (sdone) {
      case 0: kkp[0][0]=kr[0]; kkp[0][1]=kr[1]; kkp[0][2]=kr[2]; kkp[0][3]=kr[3]; break;
      case 1: kkp[1][0]=kr[0]; kkp[1][1]=kr[1]; kkp[1][2]=kr[2]; kkp[1][3]=kr[3]; break;
      case 2: kkp[2][0]=kr[0]; kkp[2][1]=kr[1]; kkp[2][2]=kr[2]; kkp[2][3]=kr[3]; break;
      case 3: kkp[3][0]=kr[0]; kkp[3][1]=kr[1]; kkp[3][2]=kr[2]; kkp[3][3]=kr[3]; break;
      case 4: kkp[4][0]=kr[0]; kkp[4][1]=kr[1]; kkp[4][2]=kr[2]; kkp[4][3]=kr[3]; break;
      default: kkp[5][0]=kr[0]; kkp[5][1]=kr[1]; kkp[5][2]=kr[2]; kkp[5][3]=kr[3]; break;
    }
  };

  auto yupd = [&](float hh, float (&yv)[8], u32 (&kkp)[6][4]) {
    float c[6];
#pragma unroll
    for (int j = 0; j < 6; ++j) c[j] = hh * BT6[j];
#pragma unroll
    for (int p = 0; p < 4; ++p) {
      float v0 = yv[2 * p], v1 = yv[2 * p + 1];
#pragma unroll
      for (int j = 0; j < 6; ++j) {
        v0 = fmaf(c[j], blo(kkp[j][p]), v0);
        v1 = fmaf(c[j], bhi(kkp[j][p]), v1);
      }
      yv[2 * p] = v0; yv[2 * p + 1] = v1;
    }
  };

#pragma unroll 1
  for (int step = 0; step < NSTEPS; ++step) {
    const float hh = hh_next;
    float cA[6] = {pcbA[0], pcbA[1], pccA[0], pccA[1], pcdA[0], pcdA[1]};
    float cB[6] = {pcbB[0], pcbB[1], pccB[0], pccB[1], pcdB[0], pcdB[1]};
    if (step + 1 < NSTEPS) {
      ld_coeff(step + 1, 0, pcbA, pccA, pcdA);
      ld_coeff(step + 1, 1, pcbB, pccB, pcdB);
      hh_next = ts[step + 2] - ts[step + 1];
    }
#pragma unroll 1
    for (int s = 0; s < 6; ++s) {
      const u32 tgt = 16u * (u32)(step * 6 + s);
      if (s > 0) gather(s - 1, 0, kkA, tgt);
      run_stage(s, hh, cA, yvA, kkA, 0);
      if (s > 0) gather(s - 1, 1, kkB, tgt);
      run_stage(s, hh, cB, yvB, kkB, 1);
    }
    const u32 tgt5 = 16u * (u32)(step * 6 + 6);
    gather(5, 0, kkA, tgt5); yupd(hh, yvA, kkA);
    gather(5, 1, kkB, tgt5); yupd(hh, yvB, kkB);
  }

  // ---- head (hs==0 WGs): softmax(y @ l2w^T + l2b) per sub ----
  if (hs == 0) {
    auto head = [&](int sub, float (&yv)[8]) {
      float* yh = (float*)w2l;
      __syncthreads();
#pragma unroll
      for (int e = 0; e < 8; ++e) yh[row_o * 132 + hb + e] = yv[e];
      __syncthreads();
      if (t < 160) {
        int r = t / 10, c = t - r * 10;
        float acc = l2b[c];
        const float* wr = l2w + (size_t)c * 128;
        for (int h2 = 0; h2 < 128; ++h2) acc = fmaf(yh[r * 132 + h2], wr[h2], acc);
        dxt[r * 12 + c] = acc;
      }
      __syncthreads();
      if (t < 16) {
        float m = dxt[t * 12];
#pragma unroll
        for (int c = 1; c < 10; ++c) m = fmaxf(m, dxt[t * 12 + c]);
        float sum = 0.f, ex[10];
#pragma unroll
        for (int c = 0; c < 10; ++c) { ex[c] = __expf(dxt[t * 12 + c] - m); sum += ex[c]; }
        float inv = 1.f / sum;
#pragma unroll
        for (int c = 0; c < 10; ++c)
          outp[(size_t)(b0r + sub * 16 + t) * 10 + c] = ex[c] * inv;
      }
    };
    head(0, yvA);
    head(1, yvB);
  }
}

extern "C" void kernel_launch(void* const* d_in, const int* in_sizes, int n_in,
                              void* d_out, int out_size, void* d_ws, size_t ws_size,
                              hipStream_t stream) {
  (void)in_sizes; (void)n_in; (void)out_size;
  if (ws_size < WS_NEED) return;

  const float* ts  = (const float*)d_in[0];
  const float* cd  = (const float*)d_in[1];
  const float* cc  = (const float*)d_in[2];
  const float* cb  = (const float*)d_in[3];
  // d_in[4] = coeff_a (unused by the reference math)
  const float* x0  = (const float*)d_in[5];
  const float* l1w = (const float*)d_in[6];
  const float* l1b = (const float*)d_in[7];
  const float* w0  = (const float*)d_in[8];
  const float* b0  = (const float*)d_in[9];
  const float* w1  = (const float*)d_in[10];
  const float* b1  = (const float*)d_in[11];
  const float* w2  = (const float*)d_in[12];
  const float* b2  = (const float*)d_in[13];
  const float* l2w = (const float*)d_in[14];
  const float* l2b = (const float*)d_in[15];

  char* ws = (char*)d_ws;
  u32* kg   = (u32*)(ws + K_OFF);
  u32* cnt  = (u32*)(ws + CNT_OFF);
  u16* w0b  = (u16*)(ws + W0_OFF);
  u16* w1b  = (u16*)(ws + W1_OFF);
  u16* w2b  = (u16*)(ws + W2_OFF);

  (void)hipMemsetAsync(cnt, 0, 16 * 256, stream);
  cvt_weights<<<4096, 256, 0, stream>>>(w0, w1, w2, w0b, w1b, w2b);
  cde_kernel<<<NWG, NTHR, 0, stream>>>(ts, cd, cc, cb, x0, l1w, l1b,
                                       b0, b1, b2, l2w, l2b,
                                       w0b, w1b, w2b, kg, cnt, (float*)d_out);
}

// Round 5
// 18589.841 us; speedup vs baseline: 8.2473x; 2.2817x over previous
//
#include <hip/hip_runtime.h>

typedef unsigned int u32;
typedef unsigned long long u64;
typedef unsigned short u16;
typedef __attribute__((ext_vector_type(8))) short bf16x8;
typedef __attribute__((ext_vector_type(4))) float f32x4;
typedef __attribute__((ext_vector_type(4))) u32 u32x4;

static constexpr int NWG    = 256;   // 16 groups x 16 h-slices
static constexpr int NTHR   = 256;
static constexpr int NSTEPS = 511;

// ---- workspace layout (bytes) ----
// kg: u32 kg[6][16][16][64]   (stage, group, h-slice, row*4+hpair) packed bf16x2
static constexpr size_t K_OFF     = 0;
static constexpr size_t KG_U32    = 6ull * 16 * 16 * 64;            // 98304
static constexpr size_t FLAGS_OFF = KG_U32 * 4;                     // 393216
static constexpr size_t W0_OFF    = FLAGS_OFF + 256ull * 64 * 4;    // flags: 256 x 256B
static constexpr size_t W1_OFF    = W0_OFF + 256 * 128 * 2;
static constexpr size_t W2_OFF    = W1_OFF + 256 * 256 * 2;
static constexpr size_t WS_NEED   = W2_OFF + 4096ull * 256 * 2;

// ---- Tsit5 tableau: constexpr so the unrolled stage loop folds to immediates ----
static constexpr float AT6c[6][6] = {
  {0.f, 0.f, 0.f, 0.f, 0.f, 0.f},
  {0.161f, 0.f, 0.f, 0.f, 0.f, 0.f},
  {-0.008480655492356989f, 0.335480655492357f, 0.f, 0.f, 0.f, 0.f},
  {2.8971530571054935f, -6.359448489975075f, 4.3622954328695815f, 0.f, 0.f, 0.f},
  {5.325864828439257f, -11.748883564062828f, 7.4955393428898365f, -0.09249506636175525f, 0.f, 0.f},
  {5.86145544294642f, -12.92096931784711f, 8.159367898576159f, -0.071584973281401f, -0.028269050394068383f, 0.f}
};
static constexpr float BT6c[6] = {
  0.09646076681806523f, 0.01f, 0.4798896504144996f, 1.379008574103742f,
  -3.290069515436081f, 2.324710524099774f
};
static constexpr float CT6c[6] = {0.f, 0.161f, 0.327f, 0.9f, 0.9800255409045097f, 1.f};

__device__ __forceinline__ u16 cvbf(float f) {
  u32 u = __float_as_uint(f);
  return (u16)((u + 0x7fffu + ((u >> 16) & 1u)) >> 16);
}
__device__ __forceinline__ float blo(u32 u) { return __uint_as_float(u << 16); }
__device__ __forceinline__ float bhi(u32 u) { return __uint_as_float(u & 0xffff0000u); }
__device__ __forceinline__ float frcp(float x) { return __builtin_amdgcn_rcpf(x); }
__device__ __forceinline__ float fsilu(float x) { return x * frcp(1.f + __expf(-x)); }
__device__ __forceinline__ float ftanh(float x) { return 1.f - 2.f * frcp(__expf(2.f * x) + 1.f); }
__device__ __forceinline__ f32x4 MF(bf16x8 a, bf16x8 b, f32x4 c) {
  return __builtin_amdgcn_mfma_f32_16x16x32_bf16(a, b, c, 0, 0, 0);
}

__global__ void cvt_weights(const float* __restrict__ w0, const float* __restrict__ w1,
                            const float* __restrict__ w2, u16* __restrict__ o0,
                            u16* __restrict__ o1, u16* __restrict__ o2) {
  int i = blockIdx.x * blockDim.x + threadIdx.x;
  if (i < 256 * 128)  o0[i] = cvbf(w0[i]);
  if (i < 256 * 256)  o1[i] = cvbf(w1[i]);
  if (i < 4096 * 256) o2[i] = cvbf(w2[i]);
}

// Persistent MFMA kernel. WG = (group g: 16 rows) x (h-slice hs: 256 GEMM3 cols).
// Exchange: packed-bf16 k slab + spread per-WG flags (relaxed bypass, no fences).
__launch_bounds__(NTHR, 1)
__global__ void cde_kernel(const float* __restrict__ ts,
                           const float* __restrict__ cdg, const float* __restrict__ ccg,
                           const float* __restrict__ cbg,
                           const float* __restrict__ x0g, const float* __restrict__ l1w,
                           const float* __restrict__ l1b,
                           const float* __restrict__ b0g, const float* __restrict__ b1g,
                           const float* __restrict__ b2g,
                           const float* __restrict__ l2w, const float* __restrict__ l2b,
                           const u16* __restrict__ w0b, const u16* __restrict__ w1b,
                           const u16* __restrict__ w2b,
                           u32* kg, u32* flags, float* __restrict__ outp) {
  __shared__ u32 w2l[32768];      // 128KB W2 frags [ks(8)][gct(16)][lane(64)][4 u32]
  __shared__ u16 ysl[16 * 128];   // 4KB  swizzled
  __shared__ u16 h1l[16 * 256];   // 8KB  swizzled
  __shared__ u16 h2l[16 * 256];   // 8KB  swizzled
  __shared__ float dxt[32 * 17];  // dX [d][row]
  __shared__ float lg[192];
  __shared__ u32 kex[1024] __attribute__((aligned(16)));  // 4KB exchange staging

  const int t  = threadIdx.x;
  const int wg = blockIdx.x;
  const int g  = wg >> 4;
  const int hs = wg & 15;
  const int b0r = g * 16;
  const int wv = t >> 6, l = t & 63, lr = l & 15, lk = l >> 4;
  const int row_o = t & 15;
  const int hb    = (t >> 4) * 8;

  // ---- persistent weight fragments ----
  bf16x8 w0f[4][4], w1f[4][8];
  float bias0v[4], bias1v[4], bias2v[4];
#pragma unroll
  for (int ct = 0; ct < 4; ++ct) {
    const int col = wv * 64 + ct * 16 + lr;
    bias0v[ct] = b0g[col];
    bias1v[ct] = b1g[col];
    bias2v[ct] = b2g[hs * 256 + col];
    const u16* base0 = w0b + (size_t)col * 128 + lk * 8;
#pragma unroll
    for (int ks = 0; ks < 4; ++ks) w0f[ct][ks] = *(const bf16x8*)(base0 + ks * 32);
    const u16* base1 = w1b + (size_t)col * 256 + lk * 8;
#pragma unroll
    for (int ks = 0; ks < 8; ++ks) w1f[ct][ks] = *(const bf16x8*)(base1 + ks * 32);
    const u16* base2 = w2b + (size_t)(hs * 256 + col) * 256 + lk * 8;
#pragma unroll
    for (int ks = 0; ks < 8; ++ks) {
      u32x4 v = *(const u32x4*)(base2 + ks * 32);
      *(u32x4*)&w2l[(size_t)((ks * 16 + wv * 4 + ct) * 64 + l) * 4] = v;
    }
  }

  // ---- y0 ----
  float yv[8];
  {
    const float* xr = x0g + (size_t)(b0r + row_o) * 32;
#pragma unroll
    for (int e = 0; e < 8; ++e) {
      float acc = l1b[hb + e];
      const float* wr = l1w + (size_t)(hb + e) * 32;
#pragma unroll
      for (int d = 0; d < 32; ++d) acc = fmaf(xr[d], wr[d], acc);
      yv[e] = acc;
    }
  }

  u32 kk[6][4];
#pragma unroll
  for (int j = 0; j < 6; ++j)
#pragma unroll
    for (int p = 0; p < 4; ++p) kk[j][p] = 0u;

  float pcb[2], pcc[2], pcd[2];
  auto ld_coeff = [&](int st) {
    size_t gi = ((size_t)(b0r + (t >> 4)) * 511 + st) * 32 + 2 * (t & 15);
    float2 vb = *(const float2*)(cbg + gi); pcb[0] = vb.x; pcb[1] = vb.y;
    float2 vc = *(const float2*)(ccg + gi); pcc[0] = vc.x; pcc[1] = vc.y;
    float2 vd = *(const float2*)(cdg + gi); pcd[0] = vd.x; pcd[1] = vd.y;
  };
  ld_coeff(0);
  float hh_next = ts[1] - ts[0];

  u32* myflag = flags + (size_t)wg * 64;
  const u32* gflags = flags + (size_t)(g * 16) * 64;
  __syncthreads();

#pragma unroll 1
  for (int step = 0; step < NSTEPS; ++step) {
    const float hh = hh_next;
    const float cb0 = pcb[0], cb1 = pcb[1];
    const float cc0 = pcc[0], cc1 = pcc[1];
    const float cd0 = pcd[0], cd1 = pcd[1];
    if (step + 1 < NSTEPS) { ld_coeff(step + 1); hh_next = ts[step + 2] - ts[step + 1]; }
    const u32 base = (u32)step * 6u;

    // wait-all(group) for stage sdone, then cooperative coalesced gather into kks
    auto gather = [&](int sdone, u32 target, u32 (&kks)[4]) {
      if (wv == 0) {
        for (;;) {
          u32 v = target;
          if (l < 16)
            v = __hip_atomic_load(&gflags[l * 64], __ATOMIC_RELAXED, __HIP_MEMORY_SCOPE_AGENT);
          if (__all((int)(v >= target))) break;
          __builtin_amdgcn_s_sleep(1);
        }
      }
      __syncthreads();
      const u64* s64 = (const u64*)(kg + (size_t)((sdone * 16 + g) * 16) * 64);
      u64 v0 = __hip_atomic_load(&s64[t],       __ATOMIC_RELAXED, __HIP_MEMORY_SCOPE_AGENT);
      u64 v1 = __hip_atomic_load(&s64[t + 256], __ATOMIC_RELAXED, __HIP_MEMORY_SCOPE_AGENT);
      u64* k64 = (u64*)kex;
      k64[t] = v0; k64[t + 256] = v1;
      __syncthreads();
      u32x4 kr = *(const u32x4*)&kex[(t >> 4) * 64 + (t & 15) * 4];
      kks[0] = kr[0]; kks[1] = kr[1]; kks[2] = kr[2]; kks[3] = kr[3];
    };

    auto run = [&](int s) {  // s is compile-time after inlining in the unrolled loop
      const float fr = CT6c[s] * hh;
      {
        int d0 = 2 * (t & 15), rl = t >> 4;
        dxt[d0 * 17 + rl]       = cb0 + fr * (2.f * cc0 + 3.f * fr * cd0);
        dxt[(d0 + 1) * 17 + rl] = cb1 + fr * (2.f * cc1 + 3.f * fr * cd1);
      }
      {
        u32 yp[4];
#pragma unroll
        for (int p = 0; p < 4; ++p) {
          float v0 = yv[2 * p], v1 = yv[2 * p + 1];
          for (int j = 0; j < s; ++j) {
            const float aj = hh * AT6c[s][j];
            v0 = fmaf(aj, blo(kk[j][p]), v0);
            v1 = fmaf(aj, bhi(kk[j][p]), v1);
          }
          yp[p] = (u32)cvbf(v0) | ((u32)cvbf(v1) << 16);
        }
        int boff = row_o * 256 + (((t >> 4) * 16) ^ ((row_o & 7) << 4));
        u32x4 w; w[0] = yp[0]; w[1] = yp[1]; w[2] = yp[2]; w[3] = yp[3];
        *(u32x4*)((char*)ysl + boff) = w;
      }
      __syncthreads();

      // GEMM1
      f32x4 acc[4];
#pragma unroll
      for (int ct = 0; ct < 4; ++ct) acc[ct] = f32x4{0.f, 0.f, 0.f, 0.f};
#pragma unroll
      for (int ks = 0; ks < 4; ++ks) {
        bf16x8 af = *(const bf16x8*)((char*)ysl + lr * 256 + ((ks * 64 + lk * 16) ^ ((lr & 7) << 4)));
#pragma unroll
        for (int ct = 0; ct < 4; ++ct) acc[ct] = MF(af, w0f[ct][ks], acc[ct]);
      }
#pragma unroll
      for (int ct = 0; ct < 4; ++ct) {
        int col = wv * 64 + ct * 16 + lr;
#pragma unroll
        for (int r = 0; r < 4; ++r) {
          int row = lk * 4 + r;
          *(u16*)((char*)h1l + row * 512 + ((col * 2) ^ ((row & 7) << 4))) =
              cvbf(fsilu(acc[ct][r] + bias0v[ct]));
        }
      }
      __syncthreads();

      // GEMM2
#pragma unroll
      for (int ct = 0; ct < 4; ++ct) acc[ct] = f32x4{0.f, 0.f, 0.f, 0.f};
#pragma unroll
      for (int ks = 0; ks < 8; ++ks) {
        bf16x8 af = *(const bf16x8*)((char*)h1l + lr * 512 + ((ks * 64 + lk * 16) ^ ((lr & 7) << 4)));
#pragma unroll
        for (int ct = 0; ct < 4; ++ct) acc[ct] = MF(af, w1f[ct][ks], acc[ct]);
      }
#pragma unroll
      for (int ct = 0; ct < 4; ++ct) {
        int col = wv * 64 + ct * 16 + lr;
#pragma unroll
        for (int r = 0; r < 4; ++r) {
          int row = lk * 4 + r;
          *(u16*)((char*)h2l + row * 512 + ((col * 2) ^ ((row & 7) << 4))) =
              cvbf(fsilu(acc[ct][r] + bias1v[ct]));
        }
      }
      __syncthreads();

      // GEMM3 + tanh + dX contract
#pragma unroll
      for (int ct = 0; ct < 4; ++ct) acc[ct] = f32x4{0.f, 0.f, 0.f, 0.f};
#pragma unroll
      for (int ks = 0; ks < 8; ++ks) {
        bf16x8 af = *(const bf16x8*)((char*)h2l + lr * 512 + ((ks * 64 + lk * 16) ^ ((lr & 7) << 4)));
#pragma unroll
        for (int ct = 0; ct < 4; ++ct) {
          bf16x8 bf = *(const bf16x8*)&w2l[(size_t)((ks * 16 + wv * 4 + ct) * 64 + l) * 4];
          acc[ct] = MF(af, bf, acc[ct]);
        }
      }
      {
        float s01[4], s23[4];
#pragma unroll
        for (int r = 0; r < 4; ++r) {
          int row = lk * 4 + r;
          float v0 = ftanh(acc[0][r] + bias2v[0]) * dxt[lr * 17 + row];
          float v1 = ftanh(acc[1][r] + bias2v[1]) * dxt[(16 + lr) * 17 + row];
          s01[r] = v0 + v1;
          float v2 = ftanh(acc[2][r] + bias2v[2]) * dxt[lr * 17 + row];
          float v3 = ftanh(acc[3][r] + bias2v[3]) * dxt[(16 + lr) * 17 + row];
          s23[r] = v2 + v3;
        }
#pragma unroll
        for (int m = 1; m < 16; m <<= 1) {
#pragma unroll
          for (int r = 0; r < 4; ++r) {
            s01[r] += __shfl_xor(s01[r], m, 64);
            s23[r] += __shfl_xor(s23[r], m, 64);
          }
        }
        if (lr == 0) {
#pragma unroll
          for (int r = 0; r < 4; ++r)
            kex[(lk * 4 + r) * 4 + wv] = (u32)cvbf(s01[r]) | ((u32)cvbf(s23[r]) << 16);
        }
      }
      __syncthreads();
      // wave 0: coalesced 256B bypass store of this WG's slice, then post flag
      const size_t slab = (size_t)((s * 16 + g) * 16 + hs) * 64;
      if (wv == 0) {
        u32 val = kex[l];
        __hip_atomic_store(&kg[slab + l], val, __ATOMIC_RELAXED, __HIP_MEMORY_SCOPE_AGENT);
      }
      asm volatile("s_waitcnt vmcnt(0)" ::: "memory");
      if (t == 0)
        __hip_atomic_store(myflag, base + (u32)s + 1u, __ATOMIC_RELAXED, __HIP_MEMORY_SCOPE_AGENT);
    };

#pragma unroll
    for (int s = 0; s < 6; ++s) {
      if (s > 0) gather(s - 1, base + (u32)s, kk[s - 1]);
      run(s);
    }
    gather(5, base + 6u, kk[5]);

    // y += h * sum_j B[j] k_j
#pragma unroll
    for (int p = 0; p < 4; ++p) {
      float v0 = yv[2 * p], v1 = yv[2 * p + 1];
#pragma unroll
      for (int j = 0; j < 6; ++j) {
        const float cj = hh * BT6c[j];
        v0 = fmaf(cj, blo(kk[j][p]), v0);
        v1 = fmaf(cj, bhi(kk[j][p]), v1);
      }
      yv[2 * p] = v0; yv[2 * p + 1] = v1;
    }
  }  // steps

  // ---- head ----
  __syncthreads();
  if (hs == 0) {
    float* yh = (float*)w2l;
#pragma unroll
    for (int e = 0; e < 8; ++e) yh[row_o * 132 + hb + e] = yv[e];
    __syncthreads();
    if (t < 160) {
      int r = t / 10, c = t - r * 10;
      float acc = l2b[c];
      const float* wr = l2w + (size_t)c * 128;
      for (int h2 = 0; h2 < 128; ++h2) acc = fmaf(yh[r * 132 + h2], wr[h2], acc);
      lg[r * 12 + c] = acc;
    }
    __syncthreads();
    if (t < 16) {
      float m = lg[t * 12];
#pragma unroll
      for (int c = 1; c < 10; ++c) m = fmaxf(m, lg[t * 12 + c]);
      float sum = 0.f, ex[10];
#pragma unroll
      for (int c = 0; c < 10; ++c) { ex[c] = __expf(lg[t * 12 + c] - m); sum += ex[c]; }
      float inv = 1.f / sum;
#pragma unroll
      for (int c = 0; c < 10; ++c) outp[(size_t)(b0r + t) * 10 + c] = ex[c] * inv;
    }
  }
}

extern "C" void kernel_launch(void* const* d_in, const int* in_sizes, int n_in,
                              void* d_out, int out_size, void* d_ws, size_t ws_size,
                              hipStream_t stream) {
  (void)in_sizes; (void)n_in; (void)out_size;
  if (ws_size < WS_NEED) return;

  const float* ts  = (const float*)d_in[0];
  const float* cd  = (const float*)d_in[1];
  const float* cc  = (const float*)d_in[2];
  const float* cb  = (const float*)d_in[3];
  // d_in[4] = coeff_a (unused by the reference math)
  const float* x0  = (const float*)d_in[5];
  const float* l1w = (const float*)d_in[6];
  const float* l1b = (const float*)d_in[7];
  const float* w0  = (const float*)d_in[8];
  const float* b0  = (const float*)d_in[9];
  const float* w1  = (const float*)d_in[10];
  const float* b1  = (const float*)d_in[11];
  const float* w2  = (const float*)d_in[12];
  const float* b2  = (const float*)d_in[13];
  const float* l2w = (const float*)d_in[14];
  const float* l2b = (const float*)d_in[15];

  char* ws = (char*)d_ws;
  u32* kg    = (u32*)(ws + K_OFF);
  u32* flags = (u32*)(ws + FLAGS_OFF);
  u16* w0b   = (u16*)(ws + W0_OFF);
  u16* w1b   = (u16*)(ws + W1_OFF);
  u16* w2b   = (u16*)(ws + W2_OFF);

  (void)hipMemsetAsync(flags, 0, 256ull * 64 * 4, stream);
  cvt_weights<<<4096, 256, 0, stream>>>(w0, w1, w2, w0b, w1b, w2b);
  cde_kernel<<<NWG, NTHR, 0, stream>>>(ts, cd, cc, cb, x0, l1w, l1b,
                                       b0, b1, b2, l2w, l2b,
                                       w0b, w1b, w2b, kg, flags, (float*)d_out);
}

// Round 6
// 14979.082 us; speedup vs baseline: 10.2354x; 1.2411x over previous
//
#include <hip/hip_runtime.h>

typedef unsigned int u32;
typedef unsigned long long u64;
typedef unsigned short u16;
typedef __attribute__((ext_vector_type(8))) short bf16x8;
typedef __attribute__((ext_vector_type(4))) float f32x4;
typedef __attribute__((ext_vector_type(4))) u32 u32x4;

static constexpr int NWG    = 256;   // 16 groups x 16 h-slices
static constexpr int NTHR   = 256;
static constexpr int NSTEPS = 511;

// ---- workspace layout (bytes) ----
// kg: u32 kg[6][16][16][64]  (stage, group, h-slice, row*4+hpair) packed tagged bf16x2
static constexpr size_t K_OFF   = 0;
static constexpr size_t KG_U32  = 6ull * 16 * 16 * 64;           // 98304
static constexpr size_t W0_OFF  = KG_U32 * 4;                    // 393216
static constexpr size_t W1_OFF  = W0_OFF + 256 * 128 * 2;
static constexpr size_t W2_OFF  = W1_OFF + 256 * 256 * 2;
static constexpr size_t WS_NEED = W2_OFF + 4096ull * 256 * 2;

// ---- Tsit5 tableau (constexpr: folds to immediates in the unrolled stage loop) ----
static constexpr float AT6c[6][6] = {
  {0.f, 0.f, 0.f, 0.f, 0.f, 0.f},
  {0.161f, 0.f, 0.f, 0.f, 0.f, 0.f},
  {-0.008480655492356989f, 0.335480655492357f, 0.f, 0.f, 0.f, 0.f},
  {2.8971530571054935f, -6.359448489975075f, 4.3622954328695815f, 0.f, 0.f, 0.f},
  {5.325864828439257f, -11.748883564062828f, 7.4955393428898365f, -0.09249506636175525f, 0.f, 0.f},
  {5.86145544294642f, -12.92096931784711f, 8.159367898576159f, -0.071584973281401f, -0.028269050394068383f, 0.f}
};
static constexpr float BT6c[6] = {
  0.09646076681806523f, 0.01f, 0.4798896504144996f, 1.379008574103742f,
  -3.290069515436081f, 2.324710524099774f
};
static constexpr float CT6c[6] = {0.f, 0.161f, 0.327f, 0.9f, 0.9800255409045097f, 1.f};

__device__ __forceinline__ u16 cvbf(float f) {
  u32 u = __float_as_uint(f);
  return (u16)((u + 0x7fffu + ((u >> 16) & 1u)) >> 16);
}
__device__ __forceinline__ u32 cvt_pk(float lo, float hi) {  // packed bf16 pair, RNE
  u32 r;
  asm("v_cvt_pk_bf16_f32 %0, %1, %2" : "=v"(r) : "v"(lo), "v"(hi));
  return r;
}
__device__ __forceinline__ float blo(u32 u) { return __uint_as_float(u << 16); }
__device__ __forceinline__ float bhi(u32 u) { return __uint_as_float(u & 0xffff0000u); }
__device__ __forceinline__ float frcp(float x) { return __builtin_amdgcn_rcpf(x); }
__device__ __forceinline__ float fsilu(float x) { return x * frcp(1.f + __expf(-x)); }
__device__ __forceinline__ float ftanh(float x) { return 1.f - 2.f * frcp(__expf(2.f * x) + 1.f); }
__device__ __forceinline__ f32x4 MF(bf16x8 a, bf16x8 b, f32x4 c) {
  return __builtin_amdgcn_mfma_f32_16x16x32_bf16(a, b, c, 0, 0, 0);
}

__global__ void cvt_weights(const float* __restrict__ w0, const float* __restrict__ w1,
                            const float* __restrict__ w2, u16* __restrict__ o0,
                            u16* __restrict__ o1, u16* __restrict__ o2) {
  int i = blockIdx.x * blockDim.x + threadIdx.x;
  if (i < 256 * 128)  o0[i] = cvbf(w0[i]);
  if (i < 256 * 256)  o1[i] = cvbf(w1[i]);
  if (i < 4096 * 256) o2[i] = cvbf(w2[i]);
}

// Persistent MFMA kernel. WG = (group g: 16 rows) x (h-slice hs: 256 GEMM3 cols).
// Exchange: single-hop tagged slab; consumers spin per-thread on their own 16B.
__launch_bounds__(NTHR, 1)
__global__ void cde_kernel(const float* __restrict__ ts,
                           const float* __restrict__ cdg, const float* __restrict__ ccg,
                           const float* __restrict__ cbg,
                           const float* __restrict__ x0g, const float* __restrict__ l1w,
                           const float* __restrict__ l1b,
                           const float* __restrict__ b0g, const float* __restrict__ b1g,
                           const float* __restrict__ b2g,
                           const float* __restrict__ l2w, const float* __restrict__ l2b,
                           const u16* __restrict__ w0b, const u16* __restrict__ w1b,
                           const u16* __restrict__ w2b,
                           u32* kg, float* __restrict__ outp) {
  __shared__ u32 w2l[32768];      // 128KB W2 frags [ks(8)][gct(16)][lane(64)][4 u32]
  __shared__ u16 ysl[16 * 128];   // 4KB  swizzled
  __shared__ u16 h1l[16 * 256];   // 8KB  swizzled
  __shared__ u16 h2l[16 * 256];   // 8KB  swizzled
  __shared__ float dxt[32 * 17];  // dX [d][row]
  __shared__ float lg[192];
  __shared__ u32 kex[1024] __attribute__((aligned(16)));  // producer staging

  const int t  = threadIdx.x;
  const int wg = blockIdx.x;
  const int g  = wg >> 4;
  const int hs = wg & 15;
  const int b0r = g * 16;
  const int wv = t >> 6, l = t & 63, lr = l & 15, lk = l >> 4;
  const int row_o = t & 15;
  const int hb    = (t >> 4) * 8;

  // ---- persistent weight fragments ----
  bf16x8 w0f[4][4], w1f[4][8];
  float bias0v[4], bias1v[4], bias2v[4];
#pragma unroll
  for (int ct = 0; ct < 4; ++ct) {
    const int col = wv * 64 + ct * 16 + lr;
    bias0v[ct] = b0g[col];
    bias1v[ct] = b1g[col];
    bias2v[ct] = b2g[hs * 256 + col];
    const u16* base0 = w0b + (size_t)col * 128 + lk * 8;
#pragma unroll
    for (int ks = 0; ks < 4; ++ks) w0f[ct][ks] = *(const bf16x8*)(base0 + ks * 32);
    const u16* base1 = w1b + (size_t)col * 256 + lk * 8;
#pragma unroll
    for (int ks = 0; ks < 8; ++ks) w1f[ct][ks] = *(const bf16x8*)(base1 + ks * 32);
    const u16* base2 = w2b + (size_t)(hs * 256 + col) * 256 + lk * 8;
#pragma unroll
    for (int ks = 0; ks < 8; ++ks) {
      u32x4 v = *(const u32x4*)(base2 + ks * 32);
      *(u32x4*)&w2l[(size_t)((ks * 16 + wv * 4 + ct) * 64 + l) * 4] = v;
    }
  }

  // ---- y0 ----
  float yv[8];
  {
    const float* xr = x0g + (size_t)(b0r + row_o) * 32;
#pragma unroll
    for (int e = 0; e < 8; ++e) {
      float acc = l1b[hb + e];
      const float* wr = l1w + (size_t)(hb + e) * 32;
#pragma unroll
      for (int d = 0; d < 32; ++d) acc = fmaf(xr[d], wr[d], acc);
      yv[e] = acc;
    }
  }

  u32 kk[6][4];
#pragma unroll
  for (int j = 0; j < 6; ++j)
#pragma unroll
    for (int p = 0; p < 4; ++p) kk[j][p] = 0u;

  float pcb[2], pcc[2], pcd[2];
  auto ld_coeff = [&](int st) {
    size_t gi = ((size_t)(b0r + (t >> 4)) * 511 + st) * 32 + 2 * (t & 15);
    float2 vb = *(const float2*)(cbg + gi); pcb[0] = vb.x; pcb[1] = vb.y;
    float2 vc = *(const float2*)(ccg + gi); pcc[0] = vc.x; pcc[1] = vc.y;
    float2 vd = *(const float2*)(cdg + gi); pcd[0] = vd.x; pcd[1] = vd.y;
  };
  ld_coeff(0);
  float hh_next = ts[1] - ts[0];
  // this thread's 16B of each (stage,group) slab: slice=t>>4, row=t&15
  const size_t myoff = (size_t)((t >> 4) * 64 + (t & 15) * 4);
  __syncthreads();

#pragma unroll 1
  for (int step = 0; step < NSTEPS; ++step) {
    const float hh = hh_next;
    const float cb0 = pcb[0], cb1 = pcb[1];
    const float cc0 = pcc[0], cc1 = pcc[1];
    const float cd0 = pcd[0], cd1 = pcd[1];
    if (step + 1 < NSTEPS) { ld_coeff(step + 1); hh_next = ts[step + 2] - ts[step + 1]; }
    const u32 tg = (u32)(step + 1) & 3u;           // per-step sequence tag
    const u32 tgins = (tg & 1u) | ((tg & 2u) << 15);  // bit0 + bit16

    // per-thread spin until this thread's 4 tagged words of stage sdone arrive
    auto spin_gather = [&](int sdone, u32 (&kks)[4]) {
      const u64* p = (const u64*)(kg + (size_t)((sdone * 16 + g) * 16) * 64 + myoff);
      u64 a, b;
      for (;;) {
        a = __hip_atomic_load(p,     __ATOMIC_RELAXED, __HIP_MEMORY_SCOPE_AGENT);
        b = __hip_atomic_load(p + 1, __ATOMIC_RELAXED, __HIP_MEMORY_SCOPE_AGENT);
        u32 a0 = (u32)a, a1 = (u32)(a >> 32), b0 = (u32)b, b1 = (u32)(b >> 32);
        u32 t0 = (a0 & 1u) | ((a0 >> 15) & 2u);
        u32 t1 = (a1 & 1u) | ((a1 >> 15) & 2u);
        u32 t2 = (b0 & 1u) | ((b0 >> 15) & 2u);
        u32 t3 = (b1 & 1u) | ((b1 >> 15) & 2u);
        if (((t0 ^ tg) | (t1 ^ tg) | (t2 ^ tg) | (t3 ^ tg)) == 0u) break;
      }
      kks[0] = (u32)a; kks[1] = (u32)(a >> 32); kks[2] = (u32)b; kks[3] = (u32)(b >> 32);
    };

    auto run = [&](int s) {  // s compile-time after unroll
      const float fr = CT6c[s] * hh;
      {
        int d0 = 2 * (t & 15), rl = t >> 4;
        dxt[d0 * 17 + rl]       = cb0 + fr * (2.f * cc0 + 3.f * fr * cd0);
        dxt[(d0 + 1) * 17 + rl] = cb1 + fr * (2.f * cc1 + 3.f * fr * cd1);
      }
      {
        u32 yp[4];
#pragma unroll
        for (int p = 0; p < 4; ++p) {
          float v0 = yv[2 * p], v1 = yv[2 * p + 1];
          for (int j = 0; j < s; ++j) {
            const float aj = hh * AT6c[s][j];
            v0 = fmaf(aj, blo(kk[j][p]), v0);
            v1 = fmaf(aj, bhi(kk[j][p]), v1);
          }
          yp[p] = cvt_pk(v0, v1);
        }
        int boff = row_o * 256 + (((t >> 4) * 16) ^ ((row_o & 7) << 4));
        u32x4 w; w[0] = yp[0]; w[1] = yp[1]; w[2] = yp[2]; w[3] = yp[3];
        *(u32x4*)((char*)ysl + boff) = w;
      }
      __syncthreads();

      // GEMM1
      f32x4 acc[4];
#pragma unroll
      for (int ct = 0; ct < 4; ++ct) acc[ct] = f32x4{0.f, 0.f, 0.f, 0.f};
#pragma unroll
      for (int ks = 0; ks < 4; ++ks) {
        bf16x8 af = *(const bf16x8*)((char*)ysl + lr * 256 + ((ks * 64 + lk * 16) ^ ((lr & 7) << 4)));
#pragma unroll
        for (int ct = 0; ct < 4; ++ct) acc[ct] = MF(af, w0f[ct][ks], acc[ct]);
      }
#pragma unroll
      for (int ct = 0; ct < 4; ++ct) {
        int col2 = (wv * 64 + ct * 16 + lr) * 2;
        int r0 = lk * 4;
        u32 p01 = cvt_pk(fsilu(acc[ct][0] + bias0v[ct]), fsilu(acc[ct][1] + bias0v[ct]));
        u32 p23 = cvt_pk(fsilu(acc[ct][2] + bias0v[ct]), fsilu(acc[ct][3] + bias0v[ct]));
        *(u16*)((char*)h1l + (r0 + 0) * 512 + (col2 ^ (((r0 + 0) & 7) << 4))) = (u16)p01;
        *(u16*)((char*)h1l + (r0 + 1) * 512 + (col2 ^ (((r0 + 1) & 7) << 4))) = (u16)(p01 >> 16);
        *(u16*)((char*)h1l + (r0 + 2) * 512 + (col2 ^ (((r0 + 2) & 7) << 4))) = (u16)p23;
        *(u16*)((char*)h1l + (r0 + 3) * 512 + (col2 ^ (((r0 + 3) & 7) << 4))) = (u16)(p23 >> 16);
      }
      __syncthreads();

      // GEMM2
#pragma unroll
      for (int ct = 0; ct < 4; ++ct) acc[ct] = f32x4{0.f, 0.f, 0.f, 0.f};
#pragma unroll
      for (int ks = 0; ks < 8; ++ks) {
        bf16x8 af = *(const bf16x8*)((char*)h1l + lr * 512 + ((ks * 64 + lk * 16) ^ ((lr & 7) << 4)));
#pragma unroll
        for (int ct = 0; ct < 4; ++ct) acc[ct] = MF(af, w1f[ct][ks], acc[ct]);
      }
#pragma unroll
      for (int ct = 0; ct < 4; ++ct) {
        int col2 = (wv * 64 + ct * 16 + lr) * 2;
        int r0 = lk * 4;
        u32 p01 = cvt_pk(fsilu(acc[ct][0] + bias1v[ct]), fsilu(acc[ct][1] + bias1v[ct]));
        u32 p23 = cvt_pk(fsilu(acc[ct][2] + bias1v[ct]), fsilu(acc[ct][3] + bias1v[ct]));
        *(u16*)((char*)h2l + (r0 + 0) * 512 + (col2 ^ (((r0 + 0) & 7) << 4))) = (u16)p01;
        *(u16*)((char*)h2l + (r0 + 1) * 512 + (col2 ^ (((r0 + 1) & 7) << 4))) = (u16)(p01 >> 16);
        *(u16*)((char*)h2l + (r0 + 2) * 512 + (col2 ^ (((r0 + 2) & 7) << 4))) = (u16)p23;
        *(u16*)((char*)h2l + (r0 + 3) * 512 + (col2 ^ (((r0 + 3) & 7) << 4))) = (u16)(p23 >> 16);
      }
      __syncthreads();

      // GEMM3 + tanh + dX contract
#pragma unroll
      for (int ct = 0; ct < 4; ++ct) acc[ct] = f32x4{0.f, 0.f, 0.f, 0.f};
#pragma unroll
      for (int ks = 0; ks < 8; ++ks) {
        bf16x8 af = *(const bf16x8*)((char*)h2l + lr * 512 + ((ks * 64 + lk * 16) ^ ((lr & 7) << 4)));
#pragma unroll
        for (int ct = 0; ct < 4; ++ct) {
          bf16x8 bf = *(const bf16x8*)&w2l[(size_t)((ks * 16 + wv * 4 + ct) * 64 + l) * 4];
          acc[ct] = MF(af, bf, acc[ct]);
        }
      }
      {
        float s01[4], s23[4];
#pragma unroll
        for (int r = 0; r < 4; ++r) {
          int row = lk * 4 + r;
          float v0 = ftanh(acc[0][r] + bias2v[0]) * dxt[lr * 17 + row];
          float v1 = ftanh(acc[1][r] + bias2v[1]) * dxt[(16 + lr) * 17 + row];
          s01[r] = v0 + v1;
          float v2 = ftanh(acc[2][r] + bias2v[2]) * dxt[lr * 17 + row];
          float v3 = ftanh(acc[3][r] + bias2v[3]) * dxt[(16 + lr) * 17 + row];
          s23[r] = v2 + v3;
        }
#pragma unroll
        for (int m = 1; m < 16; m <<= 1) {
#pragma unroll
          for (int r = 0; r < 4; ++r) {
            s01[r] += __shfl_xor(s01[r], m, 64);
            s23[r] += __shfl_xor(s23[r], m, 64);
          }
        }
        if (lr == 0) {
#pragma unroll
          for (int r = 0; r < 4; ++r)
            kex[(lk * 4 + r) * 4 + wv] = cvt_pk(s01[r], s23[r]);
        }
      }
      __syncthreads();
      // wave 0: tag + coalesced 256B relaxed store. Single hop — no drain, no flag.
      const size_t slab = (size_t)((s * 16 + g) * 16 + hs) * 64;
      if (wv == 0) {
        u32 val = (kex[l] & 0xFFFEFFFEu) | tgins;
        __hip_atomic_store(&kg[slab + l], val, __ATOMIC_RELAXED, __HIP_MEMORY_SCOPE_AGENT);
      }
    };

#pragma unroll
    for (int s = 0; s < 6; ++s) {
      if (s > 0) spin_gather(s - 1, kk[s - 1]);
      run(s);
    }
    spin_gather(5, kk[5]);

    // y += h * sum_j B[j] k_j
#pragma unroll
    for (int p = 0; p < 4; ++p) {
      float v0 = yv[2 * p], v1 = yv[2 * p + 1];
#pragma unroll
      for (int j = 0; j < 6; ++j) {
        const float cj = hh * BT6c[j];
        v0 = fmaf(cj, blo(kk[j][p]), v0);
        v1 = fmaf(cj, bhi(kk[j][p]), v1);
      }
      yv[2 * p] = v0; yv[2 * p + 1] = v1;
    }
  }  // steps

  // ---- head ----
  __syncthreads();
  if (hs == 0) {
    float* yh = (float*)w2l;
#pragma unroll
    for (int e = 0; e < 8; ++e) yh[row_o * 132 + hb + e] = yv[e];
    __syncthreads();
    if (t < 160) {
      int r = t / 10, c = t - r * 10;
      float acc = l2b[c];
      const float* wr = l2w + (size_t)c * 128;
      for (int h2 = 0; h2 < 128; ++h2) acc = fmaf(yh[r * 132 + h2], wr[h2], acc);
      lg[r * 12 + c] = acc;
    }
    __syncthreads();
    if (t < 16) {
      float m = lg[t * 12];
#pragma unroll
      for (int c = 1; c < 10; ++c) m = fmaxf(m, lg[t * 12 + c]);
      float sum = 0.f, ex[10];
#pragma unroll
      for (int c = 0; c < 10; ++c) { ex[c] = __expf(lg[t * 12 + c] - m); sum += ex[c]; }
      float inv = 1.f / sum;
#pragma unroll
      for (int c = 0; c < 10; ++c) outp[(size_t)(b0r + t) * 10 + c] = ex[c] * inv;
    }
  }
}

extern "C" void kernel_launch(void* const* d_in, const int* in_sizes, int n_in,
                              void* d_out, int out_size, void* d_ws, size_t ws_size,
                              hipStream_t stream) {
  (void)in_sizes; (void)n_in; (void)out_size;
  if (ws_size < WS_NEED) return;

  const float* ts  = (const float*)d_in[0];
  const float* cd  = (const float*)d_in[1];
  const float* cc  = (const float*)d_in[2];
  const float* cb  = (const float*)d_in[3];
  // d_in[4] = coeff_a (unused by the reference math)
  const float* x0  = (const float*)d_in[5];
  const float* l1w = (const float*)d_in[6];
  const float* l1b = (const float*)d_in[7];
  const float* w0  = (const float*)d_in[8];
  const float* b0  = (const float*)d_in[9];
  const float* w1  = (const float*)d_in[10];
  const float* b1  = (const float*)d_in[11];
  const float* w2  = (const float*)d_in[12];
  const float* b2  = (const float*)d_in[13];
  const float* l2w = (const float*)d_in[14];
  const float* l2b = (const float*)d_in[15];

  char* ws = (char*)d_ws;
  u32* kg  = (u32*)(ws + K_OFF);
  u16* w0b = (u16*)(ws + W0_OFF);
  u16* w1b = (u16*)(ws + W1_OFF);
  u16* w2b = (u16*)(ws + W2_OFF);

  // init kg to tag=3 pattern (0x01010101): never matches any step's expected tag
  // before its first write, on every call (fresh or replayed).
  (void)hipMemsetAsync(kg, 0x01, KG_U32 * 4, stream);
  cvt_weights<<<4096, 256, 0, stream>>>(w0, w1, w2, w0b, w1b, w2b);
  cde_kernel<<<NWG, NTHR, 0, stream>>>(ts, cd, cc, cb, x0, l1w, l1b,
                                       b0, b1, b2, l2w, l2b,
                                       w0b, w1b, w2b, kg, (float*)d_out);
}

// Round 7
// 12214.572 us; speedup vs baseline: 12.5519x; 1.2263x over previous
//
#include <hip/hip_runtime.h>

typedef unsigned int u32;
typedef unsigned long long u64;
typedef unsigned short u16;
typedef __attribute__((ext_vector_type(8))) short bf16x8;
typedef __attribute__((ext_vector_type(4))) float f32x4;
typedef __attribute__((ext_vector_type(4))) u32 u32x4;

static constexpr int NWG    = 256;   // 16 groups x 16 h-slices
static constexpr int NTHR   = 512;   // 8 waves -> 2 waves/SIMD at 1 WG/CU
static constexpr int NSTEPS = 511;

// ---- workspace layout (bytes) ----
// kg: u32 kg[6][16][16][64]  (stage, group, h-slice, row*4+hpair) packed tagged bf16x2
static constexpr size_t K_OFF   = 0;
static constexpr size_t KG_U32  = 6ull * 16 * 16 * 64;           // 98304
static constexpr size_t W0_OFF  = KG_U32 * 4;                    // 393216
static constexpr size_t W1_OFF  = W0_OFF + 256 * 128 * 2;
static constexpr size_t W2_OFF  = W1_OFF + 256 * 256 * 2;
static constexpr size_t WS_NEED = W2_OFF + 4096ull * 256 * 2;

// ---- Tsit5 tableau (constexpr: folds to immediates in the unrolled stage loop) ----
static constexpr float AT6c[6][6] = {
  {0.f, 0.f, 0.f, 0.f, 0.f, 0.f},
  {0.161f, 0.f, 0.f, 0.f, 0.f, 0.f},
  {-0.008480655492356989f, 0.335480655492357f, 0.f, 0.f, 0.f, 0.f},
  {2.8971530571054935f, -6.359448489975075f, 4.3622954328695815f, 0.f, 0.f, 0.f},
  {5.325864828439257f, -11.748883564062828f, 7.4955393428898365f, -0.09249506636175525f, 0.f, 0.f},
  {5.86145544294642f, -12.92096931784711f, 8.159367898576159f, -0.071584973281401f, -0.028269050394068383f, 0.f}
};
static constexpr float BT6c[6] = {
  0.09646076681806523f, 0.01f, 0.4798896504144996f, 1.379008574103742f,
  -3.290069515436081f, 2.324710524099774f
};
static constexpr float CT6c[6] = {0.f, 0.161f, 0.327f, 0.9f, 0.9800255409045097f, 1.f};

__device__ __forceinline__ u16 cvbf(float f) {
  u32 u = __float_as_uint(f);
  return (u16)((u + 0x7fffu + ((u >> 16) & 1u)) >> 16);
}
__device__ __forceinline__ u32 cvt_pk(float lo, float hi) {  // packed bf16 pair, RNE
  u32 r;
  asm("v_cvt_pk_bf16_f32 %0, %1, %2" : "=v"(r) : "v"(lo), "v"(hi));
  return r;
}
__device__ __forceinline__ float blo(u32 u) { return __uint_as_float(u << 16); }
__device__ __forceinline__ float bhi(u32 u) { return __uint_as_float(u & 0xffff0000u); }
__device__ __forceinline__ float frcp(float x) { return __builtin_amdgcn_rcpf(x); }
__device__ __forceinline__ float fsilu(float x) { return x * frcp(1.f + __expf(-x)); }
__device__ __forceinline__ float ftanh(float x) { return 1.f - 2.f * frcp(__expf(2.f * x) + 1.f); }
__device__ __forceinline__ f32x4 MF(bf16x8 a, bf16x8 b, f32x4 c) {
  return __builtin_amdgcn_mfma_f32_16x16x32_bf16(a, b, c, 0, 0, 0);
}

__global__ void cvt_weights(const float* __restrict__ w0, const float* __restrict__ w1,
                            const float* __restrict__ w2, u16* __restrict__ o0,
                            u16* __restrict__ o1, u16* __restrict__ o2) {
  int i = blockIdx.x * blockDim.x + threadIdx.x;
  if (i < 256 * 128)  o0[i] = cvbf(w0[i]);
  if (i < 256 * 256)  o1[i] = cvbf(w1[i]);
  if (i < 4096 * 256) o2[i] = cvbf(w2[i]);
}

// Persistent MFMA kernel, 8 waves/WG. WG = (group g: 16 rows) x (h-slice hs: 256 cols).
// Wave w owns cols [w*32, w*32+32): 2 ct tiles front, 2 gct tiles + h=w in GEMM3.
// Exchange: single-hop tagged slab; waves 0-3 spin per-thread on their own 16B.
__launch_bounds__(NTHR)
__global__ void cde_kernel(const float* __restrict__ ts,
                           const float* __restrict__ cdg, const float* __restrict__ ccg,
                           const float* __restrict__ cbg,
                           const float* __restrict__ x0g, const float* __restrict__ l1w,
                           const float* __restrict__ l1b,
                           const float* __restrict__ b0g, const float* __restrict__ b1g,
                           const float* __restrict__ b2g,
                           const float* __restrict__ l2w, const float* __restrict__ l2b,
                           const u16* __restrict__ w0b, const u16* __restrict__ w1b,
                           const u16* __restrict__ w2b,
                           u32* kg, float* __restrict__ outp) {
  __shared__ u32 w2l[32768];      // 128KB W2 frags [ks(8)][gct(16)][lane(64)][4 u32]
  __shared__ u16 ysl[16 * 128];   // 4KB  swizzled
  __shared__ u16 h1l[16 * 256];   // 8KB  swizzled
  __shared__ u16 h2l[16 * 256];   // 8KB  swizzled
  __shared__ float dxt[32 * 17];  // dX [d][row]
  __shared__ float lg[192];
  __shared__ u32 kexw[64];        // k assembly: [row(16)][hpair(4)], u16 halves by h

  const int t  = threadIdx.x;
  const int wg = blockIdx.x;
  const int g  = wg >> 4;
  const int hs = wg & 15;
  const int b0r = g * 16;
  const int w = t >> 6, l = t & 63, lr = l & 15, lk = l >> 4;
  const int row_o = t & 15;
  const int hb    = ((t >> 4) & 15) * 8;
  const bool act  = (t < 256);     // waves 0-3: state-owning threads

  // ---- persistent weight fragments (wave w: cols w*32 + ct*16 + lr, ct in {0,1}) ----
  bf16x8 w0f[2][4], w1f[2][8];
  float bias0v[2], bias1v[2], bias2v[2];
#pragma unroll
  for (int ct = 0; ct < 2; ++ct) {
    const int col = w * 32 + ct * 16 + lr;
    bias0v[ct] = b0g[col];
    bias1v[ct] = b1g[col];
    bias2v[ct] = b2g[hs * 256 + col];
    const u16* base0 = w0b + (size_t)col * 128 + lk * 8;
#pragma unroll
    for (int ks = 0; ks < 4; ++ks) w0f[ct][ks] = *(const bf16x8*)(base0 + ks * 32);
    const u16* base1 = w1b + (size_t)col * 256 + lk * 8;
#pragma unroll
    for (int ks = 0; ks < 8; ++ks) w1f[ct][ks] = *(const bf16x8*)(base1 + ks * 32);
    const u16* base2 = w2b + (size_t)(hs * 256 + col) * 256 + lk * 8;
#pragma unroll
    for (int ks = 0; ks < 8; ++ks) {
      u32x4 v = *(const u32x4*)(base2 + ks * 32);
      *(u32x4*)&w2l[(size_t)((ks * 16 + (w * 2 + ct)) * 64 + l) * 4] = v;
    }
  }

  // ---- y0 (valid for act threads; duplicates elsewhere, never stored) ----
  float yv[8];
  {
    const float* xr = x0g + (size_t)(b0r + row_o) * 32;
#pragma unroll
    for (int e = 0; e < 8; ++e) {
      float acc = l1b[hb + e];
      const float* wr = l1w + (size_t)(hb + e) * 32;
#pragma unroll
      for (int d = 0; d < 32; ++d) acc = fmaf(xr[d], wr[d], acc);
      yv[e] = acc;
    }
  }

  u32 kk[6][4];
#pragma unroll
  for (int j = 0; j < 6; ++j)
#pragma unroll
    for (int p = 0; p < 4; ++p) kk[j][p] = 0u;

  float pcb[2], pcc[2], pcd[2];
  auto ld_coeff = [&](int st) {
    if (!act) return;
    size_t gi = ((size_t)(b0r + (t >> 4)) * 511 + st) * 32 + 2 * (t & 15);
    float2 vb = *(const float2*)(cbg + gi); pcb[0] = vb.x; pcb[1] = vb.y;
    float2 vc = *(const float2*)(ccg + gi); pcc[0] = vc.x; pcc[1] = vc.y;
    float2 vd = *(const float2*)(cdg + gi); pcd[0] = vd.x; pcd[1] = vd.y;
  };
  pcb[0]=pcb[1]=pcc[0]=pcc[1]=pcd[0]=pcd[1]=0.f;
  ld_coeff(0);
  float hh_next = ts[1] - ts[0];
  // act thread's 16B of each (stage,group) slab: slice=t>>4, row=t&15
  const size_t myoff = (size_t)((t >> 4) * 64 + (t & 15) * 4);
  __syncthreads();

#pragma unroll 1
  for (int step = 0; step < NSTEPS; ++step) {
    const float hh = hh_next;
    const float cb0 = pcb[0], cb1 = pcb[1];
    const float cc0 = pcc[0], cc1 = pcc[1];
    const float cd0 = pcd[0], cd1 = pcd[1];
    if (step + 1 < NSTEPS) { ld_coeff(step + 1); hh_next = ts[step + 2] - ts[step + 1]; }
    const u32 tg = (u32)(step + 1) & 3u;              // per-step sequence tag
    const u32 tgins = (tg & 1u) | ((tg & 2u) << 15);  // bit0 + bit16

    // act threads spin until their 4 tagged words of stage sdone arrive
    auto spin_gather = [&](int sdone, u32 (&kks)[4]) {
      if (!act) return;
      const u64* p = (const u64*)(kg + (size_t)((sdone * 16 + g) * 16) * 64 + myoff);
      u64 a, b;
      for (;;) {
        a = __hip_atomic_load(p,     __ATOMIC_RELAXED, __HIP_MEMORY_SCOPE_AGENT);
        b = __hip_atomic_load(p + 1, __ATOMIC_RELAXED, __HIP_MEMORY_SCOPE_AGENT);
        u32 a0 = (u32)a, a1 = (u32)(a >> 32), b0 = (u32)b, b1 = (u32)(b >> 32);
        u32 t0 = (a0 & 1u) | ((a0 >> 15) & 2u);
        u32 t1 = (a1 & 1u) | ((a1 >> 15) & 2u);
        u32 t2 = (b0 & 1u) | ((b0 >> 15) & 2u);
        u32 t3 = (b1 & 1u) | ((b1 >> 15) & 2u);
        if (((t0 ^ tg) | (t1 ^ tg) | (t2 ^ tg) | (t3 ^ tg)) == 0u) break;
      }
      kks[0] = (u32)a; kks[1] = (u32)(a >> 32); kks[2] = (u32)b; kks[3] = (u32)(b >> 32);
    };

    auto run = [&](int s) {  // s compile-time after unroll
      if (act) {
        const float fr = CT6c[s] * hh;
        int d0 = 2 * (t & 15), rl = t >> 4;
        dxt[d0 * 17 + rl]       = cb0 + fr * (2.f * cc0 + 3.f * fr * cd0);
        dxt[(d0 + 1) * 17 + rl] = cb1 + fr * (2.f * cc1 + 3.f * fr * cd1);
        u32 yp[4];
#pragma unroll
        for (int p = 0; p < 4; ++p) {
          float v0 = yv[2 * p], v1 = yv[2 * p + 1];
          for (int j = 0; j < s; ++j) {
            const float aj = hh * AT6c[s][j];
            v0 = fmaf(aj, blo(kk[j][p]), v0);
            v1 = fmaf(aj, bhi(kk[j][p]), v1);
          }
          yp[p] = cvt_pk(v0, v1);
        }
        int boff = row_o * 256 + ((((t >> 4) & 15) * 16) ^ ((row_o & 7) << 4));
        u32x4 wv_; wv_[0] = yp[0]; wv_[1] = yp[1]; wv_[2] = yp[2]; wv_[3] = yp[3];
        *(u32x4*)((char*)ysl + boff) = wv_;
      }
      __syncthreads();

      // GEMM1 (per wave: 2 ct tiles)
      f32x4 acc[2];
#pragma unroll
      for (int ct = 0; ct < 2; ++ct) acc[ct] = f32x4{0.f, 0.f, 0.f, 0.f};
#pragma unroll
      for (int ks = 0; ks < 4; ++ks) {
        bf16x8 af = *(const bf16x8*)((char*)ysl + lr * 256 + ((ks * 64 + lk * 16) ^ ((lr & 7) << 4)));
#pragma unroll
        for (int ct = 0; ct < 2; ++ct) acc[ct] = MF(af, w0f[ct][ks], acc[ct]);
      }
#pragma unroll
      for (int ct = 0; ct < 2; ++ct) {
        int col2 = (w * 32 + ct * 16 + lr) * 2;
        int r0 = lk * 4;
        u32 p01 = cvt_pk(fsilu(acc[ct][0] + bias0v[ct]), fsilu(acc[ct][1] + bias0v[ct]));
        u32 p23 = cvt_pk(fsilu(acc[ct][2] + bias0v[ct]), fsilu(acc[ct][3] + bias0v[ct]));
        *(u16*)((char*)h1l + (r0 + 0) * 512 + (col2 ^ (((r0 + 0) & 7) << 4))) = (u16)p01;
        *(u16*)((char*)h1l + (r0 + 1) * 512 + (col2 ^ (((r0 + 1) & 7) << 4))) = (u16)(p01 >> 16);
        *(u16*)((char*)h1l + (r0 + 2) * 512 + (col2 ^ (((r0 + 2) & 7) << 4))) = (u16)p23;
        *(u16*)((char*)h1l + (r0 + 3) * 512 + (col2 ^ (((r0 + 3) & 7) << 4))) = (u16)(p23 >> 16);
      }
      __syncthreads();

      // GEMM2
#pragma unroll
      for (int ct = 0; ct < 2; ++ct) acc[ct] = f32x4{0.f, 0.f, 0.f, 0.f};
#pragma unroll
      for (int ks = 0; ks < 8; ++ks) {
        bf16x8 af = *(const bf16x8*)((char*)h1l + lr * 512 + ((ks * 64 + lk * 16) ^ ((lr & 7) << 4)));
#pragma unroll
        for (int ct = 0; ct < 2; ++ct) acc[ct] = MF(af, w1f[ct][ks], acc[ct]);
      }
#pragma unroll
      for (int ct = 0; ct < 2; ++ct) {
        int col2 = (w * 32 + ct * 16 + lr) * 2;
        int r0 = lk * 4;
        u32 p01 = cvt_pk(fsilu(acc[ct][0] + bias1v[ct]), fsilu(acc[ct][1] + bias1v[ct]));
        u32 p23 = cvt_pk(fsilu(acc[ct][2] + bias1v[ct]), fsilu(acc[ct][3] + bias1v[ct]));
        *(u16*)((char*)h2l + (r0 + 0) * 512 + (col2 ^ (((r0 + 0) & 7) << 4))) = (u16)p01;
        *(u16*)((char*)h2l + (r0 + 1) * 512 + (col2 ^ (((r0 + 1) & 7) << 4))) = (u16)(p01 >> 16);
        *(u16*)((char*)h2l + (r0 + 2) * 512 + (col2 ^ (((r0 + 2) & 7) << 4))) = (u16)p23;
        *(u16*)((char*)h2l + (r0 + 3) * 512 + (col2 ^ (((r0 + 3) & 7) << 4))) = (u16)(p23 >> 16);
      }
      __syncthreads();

      // GEMM3 (gct = w*2+ct) + tanh + dX contract; wave w produces h = hs*8 + w
#pragma unroll
      for (int ct = 0; ct < 2; ++ct) acc[ct] = f32x4{0.f, 0.f, 0.f, 0.f};
#pragma unroll
      for (int ks = 0; ks < 8; ++ks) {
        bf16x8 af = *(const bf16x8*)((char*)h2l + lr * 512 + ((ks * 64 + lk * 16) ^ ((lr & 7) << 4)));
#pragma unroll
        for (int ct = 0; ct < 2; ++ct) {
          bf16x8 bf = *(const bf16x8*)&w2l[(size_t)((ks * 16 + (w * 2 + ct)) * 64 + l) * 4];
          acc[ct] = MF(af, bf, acc[ct]);
        }
      }
      {
        float sv[4];
#pragma unroll
        for (int r = 0; r < 4; ++r) {
          int row = lk * 4 + r;
          sv[r] = ftanh(acc[0][r] + bias2v[0]) * dxt[lr * 17 + row] +
                  ftanh(acc[1][r] + bias2v[1]) * dxt[(16 + lr) * 17 + row];
        }
#pragma unroll
        for (int m = 1; m < 16; m <<= 1) {
#pragma unroll
          for (int r = 0; r < 4; ++r) sv[r] += __shfl_xor(sv[r], m, 64);
        }
        if (lr == 0) {
#pragma unroll
          for (int r = 0; r < 4; ++r)
            *((u16*)kexw + (lk * 4 + r) * 8 + w) = (u16)cvt_pk(sv[r], sv[r]);
        }
      }
      __syncthreads();
      // wave 0: tag + coalesced 256B relaxed store. Single hop — no drain, no flag.
      const size_t slab = (size_t)((s * 16 + g) * 16 + hs) * 64;
      if (t < 64) {
        u32 val = (kexw[l] & 0xFFFEFFFEu) | tgins;
        __hip_atomic_store(&kg[slab + l], val, __ATOMIC_RELAXED, __HIP_MEMORY_SCOPE_AGENT);
      }
    };

#pragma unroll
    for (int s = 0; s < 6; ++s) {
      if (s > 0) spin_gather(s - 1, kk[s - 1]);
      run(s);
    }
    spin_gather(5, kk[5]);

    // y += h * sum_j B[j] k_j (act threads hold real state)
#pragma unroll
    for (int p = 0; p < 4; ++p) {
      float v0 = yv[2 * p], v1 = yv[2 * p + 1];
#pragma unroll
      for (int j = 0; j < 6; ++j) {
        const float cj = hh * BT6c[j];
        v0 = fmaf(cj, blo(kk[j][p]), v0);
        v1 = fmaf(cj, bhi(kk[j][p]), v1);
      }
      yv[2 * p] = v0; yv[2 * p + 1] = v1;
    }
  }  // steps

  // ---- head ----
  __syncthreads();
  if (hs == 0) {
    float* yh = (float*)w2l;
    if (act) {
#pragma unroll
      for (int e = 0; e < 8; ++e) yh[row_o * 132 + hb + e] = yv[e];
    }
    __syncthreads();
    if (t < 160) {
      int r = t / 10, c = t - r * 10;
      float acc = l2b[c];
      const float* wr = l2w + (size_t)c * 128;
      for (int h2 = 0; h2 < 128; ++h2) acc = fmaf(yh[r * 132 + h2], wr[h2], acc);
      lg[r * 12 + c] = acc;
    }
    __syncthreads();
    if (t < 16) {
      float m = lg[t * 12];
#pragma unroll
      for (int c = 1; c < 10; ++c) m = fmaxf(m, lg[t * 12 + c]);
      float sum = 0.f, ex[10];
#pragma unroll
      for (int c = 0; c < 10; ++c) { ex[c] = __expf(lg[t * 12 + c] - m); sum += ex[c]; }
      float inv = 1.f / sum;
#pragma unroll
      for (int c = 0; c < 10; ++c) outp[(size_t)(b0r + t) * 10 + c] = ex[c] * inv;
    }
  }
}

extern "C" void kernel_launch(void* const* d_in, const int* in_sizes, int n_in,
                              void* d_out, int out_size, void* d_ws, size_t ws_size,
                              hipStream_t stream) {
  (void)in_sizes; (void)n_in; (void)out_size;
  if (ws_size < WS_NEED) return;

  const float* ts  = (const float*)d_in[0];
  const float* cd  = (const float*)d_in[1];
  const float* cc  = (const float*)d_in[2];
  const float* cb  = (const float*)d_in[3];
  // d_in[4] = coeff_a (unused by the reference math)
  const float* x0  = (const float*)d_in[5];
  const float* l1w = (const float*)d_in[6];
  const float* l1b = (const float*)d_in[7];
  const float* w0  = (const float*)d_in[8];
  const float* b0  = (const float*)d_in[9];
  const float* w1  = (const float*)d_in[10];
  const float* b1  = (const float*)d_in[11];
  const float* w2  = (const float*)d_in[12];
  const float* b2  = (const float*)d_in[13];
  const float* l2w = (const float*)d_in[14];
  const float* l2b = (const float*)d_in[15];

  char* ws = (char*)d_ws;
  u32* kg  = (u32*)(ws + K_OFF);
  u16* w0b = (u16*)(ws + W0_OFF);
  u16* w1b = (u16*)(ws + W1_OFF);
  u16* w2b = (u16*)(ws + W2_OFF);

  // init kg to tag=3 pattern (0x01010101): never matches any step's expected tag
  // before its first write, on every call (fresh or replayed).
  (void)hipMemsetAsync(kg, 0x01, KG_U32 * 4, stream);
  cvt_weights<<<4096, 256, 0, stream>>>(w0, w1, w2, w0b, w1b, w2b);
  cde_kernel<<<NWG, NTHR, 0, stream>>>(ts, cd, cc, cb, x0, l1w, l1b,
                                       b0, b1, b2, l2w, l2b,
                                       w0b, w1b, w2b, kg, (float*)d_out);
}